// Round 2
// baseline (4382.706 us; speedup 1.0000x reference)
//
#include <hip/hip_runtime.h>
#include <hip/hip_bf16.h>
#include <math.h>

#define BB 2
#define TT 1024
#define BT (BB*TT)          // 2048 rows
#define DM 1024
#define DI 2048
#define DS 128
#define NHS 32              // ssm heads
#define PDIM 64             // ssm headdim
#define NHA 16              // attn heads
#define HD 64
#define FFN_ 4096
#define NZX 4384            // 2*DI + 2*DS + NHS
#define NXBC 2304           // DI + 2*DS

// ---------------- RMSNorm (input variant: also writes copy of x) -------------
__global__ void k_rms_in(const float* __restrict__ xin, float* __restrict__ X,
                         float* __restrict__ H) {
  int row = blockIdx.x;
  int tid = threadIdx.x;          // 256 threads, 4 elems each (DM=1024)
  const float* xr = xin + (size_t)row * DM;
  float v[4]; float ss = 0.f;
  #pragma unroll
  for (int i = 0; i < 4; ++i) { v[i] = xr[tid*4+i]; ss += v[i]*v[i]; }
  __shared__ float red[256];
  red[tid] = ss; __syncthreads();
  for (int s = 128; s > 0; s >>= 1) { if (tid < s) red[tid] += red[tid+s]; __syncthreads(); }
  float scale = rsqrtf(red[0]/(float)DM + 1e-6f);
  float* Xr = X + (size_t)row*DM; float* Hr = H + (size_t)row*DM;
  #pragma unroll
  for (int i = 0; i < 4; ++i) { Xr[tid*4+i] = v[i]; Hr[tid*4+i] = v[i]*scale; }
}

__global__ void k_rms_f32(const float* __restrict__ X, float* __restrict__ H) {
  int row = blockIdx.x;
  int tid = threadIdx.x;
  const float* xr = X + (size_t)row * DM;
  float v[4]; float ss = 0.f;
  #pragma unroll
  for (int i = 0; i < 4; ++i) { v[i] = xr[tid*4+i]; ss += v[i]*v[i]; }
  __shared__ float red[256];
  red[tid] = ss; __syncthreads();
  for (int s = 128; s > 0; s >>= 1) { if (tid < s) red[tid] += red[tid+s]; __syncthreads(); }
  float scale = rsqrtf(red[0]/(float)DM + 1e-6f);
  float* Hr = H + (size_t)row*DM;
  #pragma unroll
  for (int i = 0; i < 4; ++i) Hr[tid*4+i] = v[i]*scale;
}

// ---------------- GEMM: C[M,N] = epi(A[M,K] @ W[K,N]) (+C if ADD) ------------
// A,W,C fp32 row-major. BM=BN=64, BK=16, 256 thr, 4x4/thr.
// M must be multiple of 64 (always 2048 here); N guarded.
template<int EPI, bool ADD>
__global__ void gemm_kernel(const float* __restrict__ A, const float* __restrict__ W,
                            float* __restrict__ C, int M, int N, int K) {
  __shared__ float As[16][65];
  __shared__ float Bs[16][65];
  int tid = threadIdx.x;
  int tx = tid & 15, ty = tid >> 4;
  int row0 = blockIdx.y * 64, col0 = blockIdx.x * 64;
  float acc[4][4] = {};
  for (int k0 = 0; k0 < K; k0 += 16) {
    for (int e = tid; e < 1024; e += 256) {
      int r = e >> 4, c = e & 15;
      As[c][r] = A[(size_t)(row0 + r) * K + k0 + c];
    }
    for (int e = tid; e < 1024; e += 256) {
      int r = e >> 6, c = e & 63;
      int col = col0 + c;
      Bs[r][c] = (col < N) ? W[(size_t)(k0 + r) * N + col] : 0.f;
    }
    __syncthreads();
    #pragma unroll
    for (int kk = 0; kk < 16; ++kk) {
      float a[4], b[4];
      #pragma unroll
      for (int i = 0; i < 4; ++i) a[i] = As[kk][ty*4+i];
      #pragma unroll
      for (int j = 0; j < 4; ++j) b[j] = Bs[kk][tx*4+j];
      #pragma unroll
      for (int i = 0; i < 4; ++i)
        #pragma unroll
        for (int j = 0; j < 4; ++j) acc[i][j] += a[i]*b[j];
    }
    __syncthreads();
  }
  #pragma unroll
  for (int i = 0; i < 4; ++i) {
    int r = row0 + ty*4 + i;
    #pragma unroll
    for (int j = 0; j < 4; ++j) {
      int c = col0 + tx*4 + j;
      if (c < N) {
        float v = acc[i][j];
        if (EPI == 1) { v = fmaxf(v, 0.f); v = v*v; }           // relu^2
        else if (EPI == 2) { v = 1.f/(1.f + __expf(-v)); }       // sigmoid
        float* p = &C[(size_t)r * N + c];
        if (ADD) *p += v; else *p = v;
      }
    }
  }
}

// ---------------- SSM conv (K=4) + silu + dt softplus ------------------------
__global__ void k_conv_ssm(const float* __restrict__ ZX, const float* __restrict__ cw,
                           const float* __restrict__ cb, const float* __restrict__ dtb,
                           float* __restrict__ XBC, float* __restrict__ DT) {
  int bt = blockIdx.x; int b = bt >> 10; int t = bt & 1023;
  int tid = threadIdx.x;
  for (int c = tid; c < NXBC; c += 256) {
    float acc = cb[c];
    #pragma unroll
    for (int kk = 0; kk < 4; ++kk) {
      int ts = t - 3 + kk;
      if (ts >= 0) acc += cw[c*4+kk] * ZX[((size_t)(b*TT+ts))*NZX + DI + c];
    }
    float s = acc / (1.f + __expf(-acc));  // silu
    XBC[(size_t)bt*NXBC + c] = s;
  }
  if (tid < NHS) {
    float x = ZX[(size_t)bt*NZX + (2*DI + 2*DS) + tid] + dtb[tid];
    float sp = (x > 20.f) ? x : log1pf(__expf(x));
    DT[(size_t)bt*NHS + tid] = sp;
  }
}

// ---------------- SSM scan: 64 blocks (b,h), 512 threads, state in regs ------
__global__ void k_scan(const float* __restrict__ xbc, const float* __restrict__ dt,
                       const float* __restrict__ A_log, const float* __restrict__ Dmv,
                       float* __restrict__ Y) {
  int b = blockIdx.x >> 5;
  int h = blockIdx.x & 31;
  int tid = threadIdx.x;           // 512
  int p = tid >> 3, g = tid & 7;   // p: headdim row, g: state-col group (16 each)
  float A = -__expf(A_log[h]);
  float Dmh = Dmv[h];
  __shared__ float Bs[DS], Cs[DS], xs[PDIM];
  __shared__ float dts;
  float st[16];
  #pragma unroll
  for (int j = 0; j < 16; ++j) st[j] = 0.f;
  for (int t = 0; t < TT; ++t) {
    const float* row = xbc + ((size_t)(b*TT + t)) * NXBC;
    if (tid < 128)       Bs[tid]       = row[DI + tid];
    else if (tid < 256)  Cs[tid - 128] = row[DI + DS + (tid - 128)];
    else if (tid < 320)  xs[tid - 256] = row[h*64 + (tid - 256)];
    else if (tid == 320) dts = dt[(size_t)(b*TT + t)*NHS + h];
    __syncthreads();
    float dtt = dts;
    float dA  = __expf(dtt * A);
    float dtx = dtt * xs[p];
    float acc = 0.f;
    #pragma unroll
    for (int j = 0; j < 16; ++j) {
      int n = g*16 + j;
      st[j] = st[j]*dA + dtx*Bs[n];
      acc  += st[j]*Cs[n];
    }
    acc += __shfl_xor(acc, 1);
    acc += __shfl_xor(acc, 2);
    acc += __shfl_xor(acc, 4);
    if (g == 0) Y[(size_t)(b*TT + t)*DI + h*64 + p] = acc + xs[p]*Dmh;
    __syncthreads();
  }
}

// ---------------- gate: y = rmsnorm(y * silu(z)) * mnorm_w -------------------
__global__ void k_gate(float* __restrict__ Y, const float* __restrict__ ZX,
                       const float* __restrict__ mnw) {
  int row = blockIdx.x; int tid = threadIdx.x;  // 256 thr, 8 elems each (DI=2048)
  float* yr = Y + (size_t)row*DI;
  const float* zr = ZX + (size_t)row*NZX;
  float gv[8]; float ss = 0.f;
  #pragma unroll
  for (int i = 0; i < 8; ++i) {
    int c = tid*8 + i;
    float z = zr[c];
    float sz = z / (1.f + __expf(-z));
    float v = yr[c]*sz;
    gv[i] = v; ss += v*v;
  }
  __shared__ float red[256];
  red[tid] = ss; __syncthreads();
  for (int s = 128; s > 0; s >>= 1) { if (tid < s) red[tid] += red[tid+s]; __syncthreads(); }
  float scale = rsqrtf(red[0]/(float)DI + 1e-5f);
  #pragma unroll
  for (int i = 0; i < 8; ++i) { int c = tid*8 + i; yr[c] = gv[i]*scale*mnw[c]; }
}

// ---------------- q/k/v causal dwconv (K=3) ----------------------------------
__global__ void k_conv_qkv(const float* __restrict__ QKV,
                           const float* qw, const float* qb, const float* kw, const float* kb,
                           const float* vw, const float* vb,
                           float* __restrict__ Q, float* __restrict__ Kc, float* __restrict__ Vc) {
  int bt = blockIdx.x; int b = bt >> 10; int t = bt & 1023;
  int tid = threadIdx.x;
  for (int c = tid; c < 1152; c += 256) {
    if (c < 1024) {
      int h = c >> 6, d = c & 63;
      float acc = qb[d];
      #pragma unroll
      for (int kk = 0; kk < 3; ++kk) { int ts = t-2+kk; if (ts >= 0) acc += qw[d*3+kk] * QKV[((size_t)(b*TT+ts))*1152 + c]; }
      Q[((size_t)(b*NHA + h)*TT + t)*HD + d] = acc;
    } else if (c < 1088) {
      int d = c - 1024;
      float acc = kb[d];
      #pragma unroll
      for (int kk = 0; kk < 3; ++kk) { int ts = t-2+kk; if (ts >= 0) acc += kw[d*3+kk] * QKV[((size_t)(b*TT+ts))*1152 + c]; }
      Kc[(size_t)bt*HD + d] = acc;
    } else {
      int d = c - 1088;
      float acc = vb[d];
      #pragma unroll
      for (int kk = 0; kk < 3; ++kk) { int ts = t-2+kk; if (ts >= 0) acc += vw[d*3+kk] * QKV[((size_t)(b*TT+ts))*1152 + c]; }
      Vc[(size_t)bt*HD + d] = acc;
    }
  }
}

// ---------------- attention: 1 wave per (b,h,t), online softmax --------------
__global__ void k_attn(const float* __restrict__ Q, const float* __restrict__ Kc,
                       const float* __restrict__ Vc, float* __restrict__ out) {
  int t = blockIdx.x, h = blockIdx.y, b = blockIdx.z;
  int lane = threadIdx.x;  // 64
  __shared__ float qs[64], ps[64];
  qs[lane] = Q[((size_t)(b*NHA + h)*TT + t)*HD + lane] * 0.125f;  // 1/sqrt(64)
  __syncthreads();
  float m = -INFINITY, l = 0.f, o = 0.f;
  for (int s0 = 0; s0 <= t; s0 += 64) {
    int s = s0 + lane;
    float score = -INFINITY;
    if (s <= t) {
      float acc = 0.f;
      const float* kr = &Kc[(size_t)(b*TT + s)*HD];
      #pragma unroll
      for (int d = 0; d < 64; ++d) acc += qs[d]*kr[d];
      score = acc;
    }
    float tm = score;
    #pragma unroll
    for (int off = 32; off; off >>= 1) tm = fmaxf(tm, __shfl_xor(tm, off));
    float newm = fmaxf(m, tm);
    float p = (s <= t) ? __expf(score - newm) : 0.f;
    float tsum = p;
    #pragma unroll
    for (int off = 32; off; off >>= 1) tsum += __shfl_xor(tsum, off);
    float alpha = __expf(m - newm);
    l = l*alpha + tsum;
    m = newm;
    ps[lane] = p;
    __syncthreads();
    float oacc = 0.f;
    int smax = min(63, t - s0);
    for (int ss = 0; ss <= smax; ++ss)
      oacc += ps[ss] * Vc[(size_t)(b*TT + s0 + ss)*HD + lane];
    o = o*alpha + oacc;
    __syncthreads();
  }
  out[(size_t)(b*TT + t)*DM + h*HD + lane] = o / l;
}

// ---------------- token shift ------------------------------------------------
__global__ void k_tshift(const float* __restrict__ H, const float* __restrict__ maak,
                         const float* __restrict__ maar,
                         float* __restrict__ XK, float* __restrict__ XR) {
  int idx = blockIdx.x*256 + threadIdx.x;   // B*T*DM total
  int c = idx & (DM - 1);
  int bt = idx >> 10;
  int t = bt & (TT - 1);
  float h = H[idx];
  float prev = (t > 0) ? H[idx - DM] : 0.f;
  float xx = prev - h;
  XK[idx] = h + xx*maak[c];
  XR[idx] = h + xx*maar[c];
}

// ---------------- final: out = x + sigmoid_r * kv ----------------------------
__global__ void k_final(const float* __restrict__ X, const float* __restrict__ R,
                        const float* __restrict__ KV, float* __restrict__ out) {
  int idx = blockIdx.x*256 + threadIdx.x;
  out[idx] = X[idx] + R[idx]*KV[idx];
}

// =============================================================================
extern "C" void kernel_launch(void* const* d_in, const int* in_sizes, int n_in,
                              void* d_out, int out_size, void* d_ws, size_t ws_size,
                              hipStream_t stream) {
  const float* x_in    = (const float*)d_in[0];
  const float* W_in    = (const float*)d_in[1];
  const float* conv_w  = (const float*)d_in[2];
  const float* conv_b  = (const float*)d_in[3];
  const float* A_log   = (const float*)d_in[4];
  const float* Dm      = (const float*)d_in[5];
  const float* dt_bias = (const float*)d_in[6];
  const float* mnorm_w = (const float*)d_in[7];
  const float* W_out   = (const float*)d_in[8];
  const float* W_qkv   = (const float*)d_in[9];
  const float* W_cproj = (const float*)d_in[10];
  const float* qconv_w = (const float*)d_in[11];
  const float* qconv_b = (const float*)d_in[12];
  const float* kconv_w = (const float*)d_in[13];
  const float* kconv_b = (const float*)d_in[14];
  const float* vconv_w = (const float*)d_in[15];
  const float* vconv_b = (const float*)d_in[16];
  const float* maa_k   = (const float*)d_in[17];
  const float* maa_r   = (const float*)d_in[18];
  const float* W_key   = (const float*)d_in[19];
  const float* W_rec   = (const float*)d_in[20];
  const float* W_val   = (const float*)d_in[21];
  float* out = (float*)d_out;

  float* ws = (float*)d_ws;
  float* X    = ws;                       // 2,097,152
  float* H    = X   + 2097152;            // 2,097,152
  float* ZX   = H   + 2097152;            // 8,978,432
  float* XBC  = ZX  + 8978432;            // 4,718,592
  float* DT   = XBC + 4718592;            // 65,536
  float* Y    = DT  + 65536;              // 4,194,304   (total 22,151,168 fl = 88.6 MB)
  // aliases (lifetime-disjoint reuse)
  float* QKV  = ZX;                       // after gating, ZX is dead
  float* Q    = QKV + 2359296;
  float* Kc   = Q   + 2097152;
  float* Vc   = Kc  + 131072;
  float* ATTN = XBC;                      // after scan, conv XBC is dead
  float* XK   = Y;                        // after W_out GEMM, Y is dead
  float* XR   = Y + 2097152;
  float* KF   = ZX;                       // after attention, QKV/Q/K/V dead
  float* KV   = XBC;                      // after cproj GEMM, ATTN dead
  float* R    = XBC + 2097152;

  dim3 thr256(256), thr64(64), thr512(512);

  // 1. X = x; H = rmsnorm(X)
  k_rms_in<<<BT, thr256, 0, stream>>>(x_in, X, H);
  // 2. ZX = H @ W_in  [2048,1024]x[1024,4384]
  gemm_kernel<0,false><<<dim3((NZX+63)/64, BT/64), thr256, 0, stream>>>(H, W_in, ZX, BT, NZX, DM);
  // 3. conv+silu on xBC, softplus dt
  k_conv_ssm<<<BT, thr256, 0, stream>>>(ZX, conv_w, conv_b, dt_bias, XBC, DT);
  // 4. SSM scan
  k_scan<<<BB*NHS, thr512, 0, stream>>>(XBC, DT, A_log, Dm, Y);
  // 5. gate + mnorm
  k_gate<<<BT, thr256, 0, stream>>>(Y, ZX, mnorm_w);
  // 6. X += Y @ W_out  [2048,2048]x[2048,1024]
  gemm_kernel<0,true><<<dim3(DM/64, BT/64), thr256, 0, stream>>>(Y, W_out, X, BT, DM, DI);
  // 7. H = rmsnorm(X)
  k_rms_f32<<<BT, thr256, 0, stream>>>(X, H);
  // 8. QKV = H @ W_qkv  [2048,1024]x[1024,1152]
  gemm_kernel<0,false><<<dim3(1152/64, BT/64), thr256, 0, stream>>>(H, W_qkv, QKV, BT, 1152, DM);
  // 9. q/k/v convs
  k_conv_qkv<<<BT, thr256, 0, stream>>>(QKV, qconv_w, qconv_b, kconv_w, kconv_b, vconv_w, vconv_b, Q, Kc, Vc);
  // 10. attention
  k_attn<<<dim3(TT, NHA, BB), thr64, 0, stream>>>(Q, Kc, Vc, ATTN);
  // 11. X += ATTN @ W_cproj
  gemm_kernel<0,true><<<dim3(DM/64, BT/64), thr256, 0, stream>>>(ATTN, W_cproj, X, BT, DM, DM);
  // 12. H = rmsnorm(X)
  k_rms_f32<<<BT, thr256, 0, stream>>>(X, H);
  // 13. token shift
  k_tshift<<<(BT*DM)/256, thr256, 0, stream>>>(H, maa_k, maa_r, XK, XR);
  // 14. KF = relu(XK @ W_key)^2  [2048,1024]x[1024,4096]
  gemm_kernel<1,false><<<dim3(FFN_/64, BT/64), thr256, 0, stream>>>(XK, W_key, KF, BT, FFN_, DM);
  // 15. KV = KF @ W_val  [2048,4096]x[4096,1024]
  gemm_kernel<0,false><<<dim3(DM/64, BT/64), thr256, 0, stream>>>(KF, W_val, KV, BT, DM, FFN_);
  // 16. R = sigmoid(XR @ W_rec)
  gemm_kernel<2,false><<<dim3(DM/64, BT/64), thr256, 0, stream>>>(XR, W_rec, R, BT, DM, DM);
  // 17. out = x + sigmoid_r * kv
  k_final<<<(BT*DM)/256, thr256, 0, stream>>>(X, R, KV, out);
}

// Round 3
// 1932.024 us; speedup vs baseline: 2.2685x; 2.2685x over previous
//
#include <hip/hip_runtime.h>
#include <hip/hip_bf16.h>
#include <math.h>

#define BB 2
#define TT 1024
#define BT (BB*TT)          // 2048 rows
#define DM 1024
#define DI 2048
#define DS 128
#define NHS 32              // ssm heads
#define PDIM 64             // ssm headdim
#define NHA 16              // attn heads
#define HD 64
#define FFN_ 4096
#define NZX 4384            // 2*DI + 2*DS + NHS
#define NXBC 2304           // DI + 2*DS

typedef __hip_bfloat16 bf16;
typedef short bf16x8 __attribute__((ext_vector_type(8)));
typedef float f32x4 __attribute__((ext_vector_type(4)));

__device__ __forceinline__ float b2f(bf16 v){ return __bfloat162float(v); }
__device__ __forceinline__ bf16 f2b(float v){ return __float2bfloat16(v); }

// ---------------- RMSNorm: write fp32 X copy + bf16 normalized H -------------
__global__ void k_rms_in(const float* __restrict__ xin, float* __restrict__ X,
                         bf16* __restrict__ H) {
  int row = blockIdx.x;
  int tid = threadIdx.x;          // 256 threads, 4 elems each (DM=1024)
  const float* xr = xin + (size_t)row * DM;
  float v[4]; float ss = 0.f;
  #pragma unroll
  for (int i = 0; i < 4; ++i) { v[i] = xr[tid*4+i]; ss += v[i]*v[i]; }
  __shared__ float red[256];
  red[tid] = ss; __syncthreads();
  for (int s = 128; s > 0; s >>= 1) { if (tid < s) red[tid] += red[tid+s]; __syncthreads(); }
  float scale = rsqrtf(red[0]/(float)DM + 1e-6f);
  float* Xr = X + (size_t)row*DM; bf16* Hr = H + (size_t)row*DM;
  #pragma unroll
  for (int i = 0; i < 4; ++i) { Xr[tid*4+i] = v[i]; Hr[tid*4+i] = f2b(v[i]*scale); }
}

__global__ void k_rms_f32(const float* __restrict__ X, bf16* __restrict__ H) {
  int row = blockIdx.x;
  int tid = threadIdx.x;
  const float* xr = X + (size_t)row * DM;
  float v[4]; float ss = 0.f;
  #pragma unroll
  for (int i = 0; i < 4; ++i) { v[i] = xr[tid*4+i]; ss += v[i]*v[i]; }
  __shared__ float red[256];
  red[tid] = ss; __syncthreads();
  for (int s = 128; s > 0; s >>= 1) { if (tid < s) red[tid] += red[tid+s]; __syncthreads(); }
  float scale = rsqrtf(red[0]/(float)DM + 1e-6f);
  bf16* Hr = H + (size_t)row*DM;
  #pragma unroll
  for (int i = 0; i < 4; ++i) Hr[tid*4+i] = f2b(v[i]*scale);
}

// ---------------- weight cast + transpose: Wt[n][k] = bf16(W[k][n]) ----------
// grid (Npad/32, K/32), block (32,8). Zero-fills n >= N.
__global__ void k_tcast(const float* __restrict__ W, bf16* __restrict__ Wt,
                        int K, int N) {
  __shared__ float t[32][33];
  int tx = threadIdx.x, ty = threadIdx.y;
  int n0 = blockIdx.x*32, k0 = blockIdx.y*32;
  #pragma unroll
  for (int i = 0; i < 4; ++i) {
    int k = k0 + ty + i*8, n = n0 + tx;
    t[ty + i*8][tx] = (n < N) ? W[(size_t)k*N + n] : 0.f;
  }
  __syncthreads();
  #pragma unroll
  for (int i = 0; i < 4; ++i) {
    int n = n0 + ty + i*8, k = k0 + tx;
    Wt[(size_t)n*K + k] = f2b(t[tx][ty + i*8]);
  }
}

// ---------------- MFMA GEMM: C[M,N] = epi(A[M,K] @ Bt[N,K]^T) ----------------
// A bf16 row-major, Bt bf16 row-major (N x K). 128x128 tile, BK=32,
// 256 threads = 4 waves, each wave 64x64 via 4x4 of 16x16x32 bf16 MFMA.
// M % 128 == 0; K % 32 == 0; grid.x covers padded N, stores guarded col < N.
template<int EPI, bool ADD, bool OUTBF>
__global__ __launch_bounds__(256)
void mfma_gemm(const bf16* __restrict__ A, const bf16* __restrict__ Bt,
               float* __restrict__ C, bf16* __restrict__ Cbf,
               int M, int N, int K) {
  __shared__ bf16 As[128*32];
  __shared__ bf16 Bs[128*32];
  int tid = threadIdx.x;
  int wave = tid >> 6, lane = tid & 63;
  int m_l = lane & 15, quad = lane >> 4;
  int wr = (wave & 1) * 64, wc = (wave >> 1) * 64;
  int row0 = blockIdx.y * 128, col0 = blockIdx.x * 128;
  f32x4 acc[4][4];
  #pragma unroll
  for (int i = 0; i < 4; ++i)
    #pragma unroll
    for (int j = 0; j < 4; ++j) acc[i][j] = (f32x4){0.f,0.f,0.f,0.f};
  int r_a = tid >> 2;            // 0..63
  int kc  = (tid & 3) * 8;       // 0,8,16,24
  for (int k0 = 0; k0 < K; k0 += 32) {
    uint4 av0 = *(const uint4*)&A [(size_t)(row0      + r_a) * K + k0 + kc];
    uint4 av1 = *(const uint4*)&A [(size_t)(row0 + 64 + r_a) * K + k0 + kc];
    uint4 bv0 = *(const uint4*)&Bt[(size_t)(col0      + r_a) * K + k0 + kc];
    uint4 bv1 = *(const uint4*)&Bt[(size_t)(col0 + 64 + r_a) * K + k0 + kc];
    __syncthreads();
    *(uint4*)&As[(     r_a) * 32 + kc] = av0;
    *(uint4*)&As[(64 + r_a) * 32 + kc] = av1;
    *(uint4*)&Bs[(     r_a) * 32 + kc] = bv0;
    *(uint4*)&Bs[(64 + r_a) * 32 + kc] = bv1;
    __syncthreads();
    bf16x8 af[4], bfv[4];
    #pragma unroll
    for (int i = 0; i < 4; ++i) af[i]  = *(const bf16x8*)&As[(wr + i*16 + m_l)*32 + quad*8];
    #pragma unroll
    for (int j = 0; j < 4; ++j) bfv[j] = *(const bf16x8*)&Bs[(wc + j*16 + m_l)*32 + quad*8];
    #pragma unroll
    for (int i = 0; i < 4; ++i)
      #pragma unroll
      for (int j = 0; j < 4; ++j)
        acc[i][j] = __builtin_amdgcn_mfma_f32_16x16x32_bf16(af[i], bfv[j], acc[i][j], 0, 0, 0);
  }
  #pragma unroll
  for (int i = 0; i < 4; ++i) {
    #pragma unroll
    for (int j = 0; j < 4; ++j) {
      int col = col0 + wc + j*16 + m_l;
      if (col < N) {
        #pragma unroll
        for (int r = 0; r < 4; ++r) {
          int row = row0 + wr + i*16 + quad*4 + r;
          float v = acc[i][j][r];
          if (EPI == 1) { v = fmaxf(v, 0.f); v = v*v; }          // relu^2
          else if (EPI == 2) v = 1.f/(1.f + __expf(-v));          // sigmoid
          if (OUTBF)      Cbf[(size_t)row*N + col] = f2b(v);
          else if (ADD)   C[(size_t)row*N + col] += v;
          else            C[(size_t)row*N + col]  = v;
        }
      }
    }
  }
}

// ---------------- SSM conv (K=4) + silu + dt softplus ------------------------
__global__ void k_conv_ssm(const float* __restrict__ ZX, const float* __restrict__ cw,
                           const float* __restrict__ cb, const float* __restrict__ dtb,
                           float* __restrict__ XBC, float* __restrict__ DT) {
  int bt = blockIdx.x; int b = bt >> 10; int t = bt & 1023;
  int tid = threadIdx.x;
  for (int c = tid; c < NXBC; c += 256) {
    float acc = cb[c];
    #pragma unroll
    for (int kk = 0; kk < 4; ++kk) {
      int ts = t - 3 + kk;
      if (ts >= 0) acc += cw[c*4+kk] * ZX[((size_t)(b*TT+ts))*NZX + DI + c];
    }
    float s = acc / (1.f + __expf(-acc));  // silu
    XBC[(size_t)bt*NXBC + c] = s;
  }
  if (tid < NHS) {
    float x = ZX[(size_t)bt*NZX + (2*DI + 2*DS) + tid] + dtb[tid];
    float sp = (x > 20.f) ? x : log1pf(__expf(x));
    DT[(size_t)bt*NHS + tid] = sp;
  }
}

// ---------------- SSM scan: 64 blocks (b,h), 512 threads, state in regs ------
__global__ void k_scan(const float* __restrict__ xbc, const float* __restrict__ dt,
                       const float* __restrict__ A_log, const float* __restrict__ Dmv,
                       float* __restrict__ Y) {
  int b = blockIdx.x >> 5;
  int h = blockIdx.x & 31;
  int tid = threadIdx.x;           // 512
  int p = tid >> 3, g = tid & 7;   // p: headdim row, g: state-col group (16 each)
  float A = -__expf(A_log[h]);
  float Dmh = Dmv[h];
  __shared__ float Bs[DS], Cs[DS], xs[PDIM];
  __shared__ float dts;
  float st[16];
  #pragma unroll
  for (int j = 0; j < 16; ++j) st[j] = 0.f;
  for (int t = 0; t < TT; ++t) {
    const float* row = xbc + ((size_t)(b*TT + t)) * NXBC;
    if (tid < 128)       Bs[tid]       = row[DI + tid];
    else if (tid < 256)  Cs[tid - 128] = row[DI + DS + (tid - 128)];
    else if (tid < 320)  xs[tid - 256] = row[h*64 + (tid - 256)];
    else if (tid == 320) dts = dt[(size_t)(b*TT + t)*NHS + h];
    __syncthreads();
    float dtt = dts;
    float dA  = __expf(dtt * A);
    float dtx = dtt * xs[p];
    float acc = 0.f;
    #pragma unroll
    for (int j = 0; j < 16; ++j) {
      int n = g*16 + j;
      st[j] = st[j]*dA + dtx*Bs[n];
      acc  += st[j]*Cs[n];
    }
    acc += __shfl_xor(acc, 1);
    acc += __shfl_xor(acc, 2);
    acc += __shfl_xor(acc, 4);
    if (g == 0) Y[(size_t)(b*TT + t)*DI + h*64 + p] = acc + xs[p]*Dmh;
    __syncthreads();
  }
}

// ---------------- gate: Ybf = bf16(rmsnorm(y * silu(z)) * mnorm_w) -----------
__global__ void k_gate(const float* __restrict__ Y, const float* __restrict__ ZX,
                       const float* __restrict__ mnw, bf16* __restrict__ Ybf) {
  int row = blockIdx.x; int tid = threadIdx.x;  // 256 thr, 8 elems each (DI=2048)
  const float* yr = Y + (size_t)row*DI;
  const float* zr = ZX + (size_t)row*NZX;
  float gv[8]; float ss = 0.f;
  #pragma unroll
  for (int i = 0; i < 8; ++i) {
    int c = tid*8 + i;
    float z = zr[c];
    float sz = z / (1.f + __expf(-z));
    float v = yr[c]*sz;
    gv[i] = v; ss += v*v;
  }
  __shared__ float red[256];
  red[tid] = ss; __syncthreads();
  for (int s = 128; s > 0; s >>= 1) { if (tid < s) red[tid] += red[tid+s]; __syncthreads(); }
  float scale = rsqrtf(red[0]/(float)DI + 1e-5f);
  bf16* br = Ybf + (size_t)row*DI;
  #pragma unroll
  for (int i = 0; i < 8; ++i) { int c = tid*8 + i; br[c] = f2b(gv[i]*scale*mnw[c]); }
}

// ---------------- q/k/v causal dwconv (K=3) ----------------------------------
__global__ void k_conv_qkv(const float* __restrict__ QKV,
                           const float* qw, const float* qb, const float* kw, const float* kb,
                           const float* vw, const float* vb,
                           float* __restrict__ Q, float* __restrict__ Kc, float* __restrict__ Vc) {
  int bt = blockIdx.x; int b = bt >> 10; int t = bt & 1023;
  int tid = threadIdx.x;
  for (int c = tid; c < 1152; c += 256) {
    if (c < 1024) {
      int h = c >> 6, d = c & 63;
      float acc = qb[d];
      #pragma unroll
      for (int kk = 0; kk < 3; ++kk) { int ts = t-2+kk; if (ts >= 0) acc += qw[d*3+kk] * QKV[((size_t)(b*TT+ts))*1152 + c]; }
      Q[((size_t)(b*NHA + h)*TT + t)*HD + d] = acc;
    } else if (c < 1088) {
      int d = c - 1024;
      float acc = kb[d];
      #pragma unroll
      for (int kk = 0; kk < 3; ++kk) { int ts = t-2+kk; if (ts >= 0) acc += kw[d*3+kk] * QKV[((size_t)(b*TT+ts))*1152 + c]; }
      Kc[(size_t)bt*HD + d] = acc;
    } else {
      int d = c - 1088;
      float acc = vb[d];
      #pragma unroll
      for (int kk = 0; kk < 3; ++kk) { int ts = t-2+kk; if (ts >= 0) acc += vw[d*3+kk] * QKV[((size_t)(b*TT+ts))*1152 + c]; }
      Vc[(size_t)bt*HD + d] = acc;
    }
  }
}

// ---------------- attention: 1 wave per (b,h,t), online softmax, bf16 out ----
__global__ void k_attn(const float* __restrict__ Q, const float* __restrict__ Kc,
                       const float* __restrict__ Vc, bf16* __restrict__ out) {
  int t = blockIdx.x, h = blockIdx.y, b = blockIdx.z;
  int lane = threadIdx.x;  // 64
  __shared__ float qs[64], ps[64];
  qs[lane] = Q[((size_t)(b*NHA + h)*TT + t)*HD + lane] * 0.125f;  // 1/sqrt(64)
  __syncthreads();
  float m = -INFINITY, l = 0.f, o = 0.f;
  for (int s0 = 0; s0 <= t; s0 += 64) {
    int s = s0 + lane;
    float score = -INFINITY;
    if (s <= t) {
      float acc = 0.f;
      const float* kr = &Kc[(size_t)(b*TT + s)*HD];
      #pragma unroll
      for (int d = 0; d < 64; ++d) acc += qs[d]*kr[d];
      score = acc;
    }
    float tm = score;
    #pragma unroll
    for (int off = 32; off; off >>= 1) tm = fmaxf(tm, __shfl_xor(tm, off));
    float newm = fmaxf(m, tm);
    float p = (s <= t) ? __expf(score - newm) : 0.f;
    float tsum = p;
    #pragma unroll
    for (int off = 32; off; off >>= 1) tsum += __shfl_xor(tsum, off);
    float alpha = __expf(m - newm);
    l = l*alpha + tsum;
    m = newm;
    ps[lane] = p;
    __syncthreads();
    float oacc = 0.f;
    int smax = min(63, t - s0);
    for (int ss = 0; ss <= smax; ++ss)
      oacc += ps[ss] * Vc[(size_t)(b*TT + s0 + ss)*HD + lane];
    o = o*alpha + oacc;
    __syncthreads();
  }
  out[(size_t)(b*TT + t)*DM + h*HD + lane] = f2b(o / l);
}

// ---------------- token shift (bf16 in/out) ----------------------------------
__global__ void k_tshift(const bf16* __restrict__ H, const float* __restrict__ maak,
                         const float* __restrict__ maar,
                         bf16* __restrict__ XK, bf16* __restrict__ XR) {
  int idx = blockIdx.x*256 + threadIdx.x;   // B*T*DM total
  int c = idx & (DM - 1);
  int bt = idx >> 10;
  int t = bt & (TT - 1);
  float h = b2f(H[idx]);
  float prev = (t > 0) ? b2f(H[idx - DM]) : 0.f;
  float xx = prev - h;
  XK[idx] = f2b(h + xx*maak[c]);
  XR[idx] = f2b(h + xx*maar[c]);
}

// ---------------- final: out = x + sigmoid_r * kv ----------------------------
__global__ void k_final(const float* __restrict__ X, const float* __restrict__ R,
                        const float* __restrict__ KV, float* __restrict__ out) {
  int idx = blockIdx.x*256 + threadIdx.x;
  out[idx] = X[idx] + R[idx]*KV[idx];
}

// =============================================================================
extern "C" void kernel_launch(void* const* d_in, const int* in_sizes, int n_in,
                              void* d_out, int out_size, void* d_ws, size_t ws_size,
                              hipStream_t stream) {
  const float* x_in    = (const float*)d_in[0];
  const float* W_in    = (const float*)d_in[1];
  const float* conv_w  = (const float*)d_in[2];
  const float* conv_b  = (const float*)d_in[3];
  const float* A_log   = (const float*)d_in[4];
  const float* Dm      = (const float*)d_in[5];
  const float* dt_bias = (const float*)d_in[6];
  const float* mnorm_w = (const float*)d_in[7];
  const float* W_out   = (const float*)d_in[8];
  const float* W_qkv   = (const float*)d_in[9];
  const float* W_cproj = (const float*)d_in[10];
  const float* qconv_w = (const float*)d_in[11];
  const float* qconv_b = (const float*)d_in[12];
  const float* kconv_w = (const float*)d_in[13];
  const float* kconv_b = (const float*)d_in[14];
  const float* vconv_w = (const float*)d_in[15];
  const float* vconv_b = (const float*)d_in[16];
  const float* maa_k   = (const float*)d_in[17];
  const float* maa_r   = (const float*)d_in[18];
  const float* W_key   = (const float*)d_in[19];
  const float* W_rec   = (const float*)d_in[20];
  const float* W_val   = (const float*)d_in[21];
  float* out = (float*)d_out;

  float* ws = (float*)d_ws;
  // persistent fp32/bf16 regions (float-unit offsets)
  float* X    = ws;                        // [0, 2,097,152)
  bf16*  Hbf  = (bf16*)(ws + 2097152);     // 2,097,152 el -> [.., +1,048,576 fl)
  float* ZX   = ws + 3145728;              // [3,145,728, 12,124,160)
  float* XBC  = ws + 12124160;             // [12,124,160, 16,842,752)
  float* DT   = ws + 16842752;             // [.., +65,536)
  float* Y    = ws + 16908288;             // [16,908,288, 21,102,592)  ~84.4MB total

  // lifetime-disjoint aliases
  bf16*  Wt_in    = (bf16*)XBC;                     // step 2  (4480x1024 el)
  bf16*  Ybf      = (bf16*)XBC;                     // step 5-6 (2048x2048 el)
  bf16*  Wt_out   = (bf16*)(XBC + 2621440);         // step 6  (1024x2048 el)
  float* QKV      = ZX;                             // step 8-9 (2048x1152)
  float* Q        = ZX + 2359296;                   // 2048x1024
  float* Kc       = ZX + 4456448;                   // 2048x64
  float* Vc       = ZX + 4587520;                   // 2048x64
  bf16*  Wt_qkv   = (bf16*)XBC;                     // step 8  (1152x1024 el)
  bf16*  ATTNbf   = (bf16*)XBC;                     // step 10-11 (2048x1024 el)
  bf16*  Wt_cproj = (bf16*)(XBC + 1310720);         // step 11 (1024x1024 el)
  bf16*  XKbf     = (bf16*)Y;                       // step 13+ (2048x1024 el)
  bf16*  XRbf     = (bf16*)(Y + 1048576);           // step 13+ (2048x1024 el)
  bf16*  KFbf     = (bf16*)ZX;                      // step 14-15 (2048x4096 el)
  bf16*  Wt_late  = (bf16*)(ZX + 4718592);          // steps 14-16 (<=4096x1024 el)
  float* KV       = XBC;                            // step 15-17 (2048x1024)
  float* R        = XBC + 2097152;                  // step 16-17 (2048x1024)

  dim3 thr256(256), thr64(64), thr512(512);
  dim3 tblk(32, 8);

  // 1. X = x; Hbf = rmsnorm(x)
  k_rms_in<<<BT, thr256, 0, stream>>>(x_in, X, Hbf);
  // 2. ZX = Hbf @ W_in  [2048,1024]x[1024,4384] (N padded to 4480)
  k_tcast<<<dim3(4480/32, 1024/32), tblk, 0, stream>>>(W_in, Wt_in, 1024, NZX);
  mfma_gemm<0,false,false><<<dim3(4480/128, BT/128), thr256, 0, stream>>>(Hbf, Wt_in, ZX, nullptr, BT, NZX, 1024);
  // 3. conv+silu on xBC, softplus dt
  k_conv_ssm<<<BT, thr256, 0, stream>>>(ZX, conv_w, conv_b, dt_bias, XBC, DT);
  // 4. SSM scan
  k_scan<<<BB*NHS, thr512, 0, stream>>>(XBC, DT, A_log, Dm, Y);
  // 5. gate + mnorm -> Ybf
  k_gate<<<BT, thr256, 0, stream>>>(Y, ZX, mnorm_w, Ybf);
  // 6. X += Ybf @ W_out  [2048,2048]x[2048,1024]
  k_tcast<<<dim3(1024/32, 2048/32), tblk, 0, stream>>>(W_out, Wt_out, 2048, 1024);
  mfma_gemm<0,true,false><<<dim3(1024/128, BT/128), thr256, 0, stream>>>(Ybf, Wt_out, X, nullptr, BT, 1024, 2048);
  // 7. Hbf = rmsnorm(X)
  k_rms_f32<<<BT, thr256, 0, stream>>>(X, Hbf);
  // 8. QKV = Hbf @ W_qkv  [2048,1024]x[1024,1152]
  k_tcast<<<dim3(1152/32, 1024/32), tblk, 0, stream>>>(W_qkv, Wt_qkv, 1024, 1152);
  mfma_gemm<0,false,false><<<dim3(1152/128, BT/128), thr256, 0, stream>>>(Hbf, Wt_qkv, QKV, nullptr, BT, 1152, 1024);
  // 9. q/k/v convs
  k_conv_qkv<<<BT, thr256, 0, stream>>>(QKV, qconv_w, qconv_b, kconv_w, kconv_b, vconv_w, vconv_b, Q, Kc, Vc);
  // 10. attention -> ATTNbf
  k_attn<<<dim3(TT, NHA, BB), thr64, 0, stream>>>(Q, Kc, Vc, ATTNbf);
  // 11. X += ATTNbf @ W_cproj
  k_tcast<<<dim3(1024/32, 1024/32), tblk, 0, stream>>>(W_cproj, Wt_cproj, 1024, 1024);
  mfma_gemm<0,true,false><<<dim3(1024/128, BT/128), thr256, 0, stream>>>(ATTNbf, Wt_cproj, X, nullptr, BT, 1024, 1024);
  // 12. Hbf = rmsnorm(X)
  k_rms_f32<<<BT, thr256, 0, stream>>>(X, Hbf);
  // 13. token shift -> XKbf, XRbf
  k_tshift<<<(BT*DM)/256, thr256, 0, stream>>>(Hbf, maa_k, maa_r, XKbf, XRbf);
  // 14. KFbf = bf16(relu(XKbf @ W_key)^2)  [2048,1024]x[1024,4096]
  k_tcast<<<dim3(4096/32, 1024/32), tblk, 0, stream>>>(W_key, Wt_late, 1024, 4096);
  mfma_gemm<1,false,true><<<dim3(4096/128, BT/128), thr256, 0, stream>>>(XKbf, Wt_late, nullptr, KFbf, BT, 4096, 1024);
  // 15. KV = KFbf @ W_val  [2048,4096]x[4096,1024]
  k_tcast<<<dim3(1024/32, 4096/32), tblk, 0, stream>>>(W_val, Wt_late, 4096, 1024);
  mfma_gemm<0,false,false><<<dim3(1024/128, BT/128), thr256, 0, stream>>>(KFbf, Wt_late, KV, nullptr, BT, 1024, 4096);
  // 16. R = sigmoid(XRbf @ W_rec)
  k_tcast<<<dim3(1024/32, 1024/32), tblk, 0, stream>>>(W_rec, Wt_late, 1024, 1024);
  mfma_gemm<2,false,false><<<dim3(1024/128, BT/128), thr256, 0, stream>>>(XRbf, Wt_late, R, nullptr, BT, 1024, 1024);
  // 17. out = x + sigmoid_r * kv
  k_final<<<(BT*DM)/256, thr256, 0, stream>>>(X, R, KV, out);
}

// Round 4
// 1375.035 us; speedup vs baseline: 3.1873x; 1.4051x over previous
//
#include <hip/hip_runtime.h>
#include <hip/hip_bf16.h>
#include <math.h>

#define BB 2
#define TT 1024
#define BT (BB*TT)          // 2048 rows
#define DM 1024
#define DI 2048
#define DS 128
#define NHS 32              // ssm heads
#define PDIM 64             // ssm headdim
#define NHA 16              // attn heads
#define HD 64
#define FFN_ 4096
#define NZX 4384            // 2*DI + 2*DS + NHS
#define NXBC 2304           // DI + 2*DS
#define NXBCD 2336          // xBC (2304) + dt (32) raw gemm-out width
#define CL 128              // scan chunk length
#define NC 8                // chunks

typedef __hip_bfloat16 bf16;
typedef short bf16x8 __attribute__((ext_vector_type(8)));
typedef float f32x4 __attribute__((ext_vector_type(4)));

__device__ __forceinline__ float b2f(bf16 v){ return __bfloat162float(v); }
__device__ __forceinline__ bf16 f2b(float v){ return __float2bfloat16(v); }

// ---------------- RMSNorm: write fp32 X copy + bf16 normalized H -------------
__global__ void k_rms_in(const float* __restrict__ xin, float* __restrict__ X,
                         bf16* __restrict__ H) {
  int row = blockIdx.x;
  int tid = threadIdx.x;          // 256 threads, 4 elems each (DM=1024)
  const float* xr = xin + (size_t)row * DM;
  float v[4]; float ss = 0.f;
  #pragma unroll
  for (int i = 0; i < 4; ++i) { v[i] = xr[tid*4+i]; ss += v[i]*v[i]; }
  __shared__ float red[256];
  red[tid] = ss; __syncthreads();
  for (int s = 128; s > 0; s >>= 1) { if (tid < s) red[tid] += red[tid+s]; __syncthreads(); }
  float scale = rsqrtf(red[0]/(float)DM + 1e-6f);
  float* Xr = X + (size_t)row*DM; bf16* Hr = H + (size_t)row*DM;
  #pragma unroll
  for (int i = 0; i < 4; ++i) { Xr[tid*4+i] = v[i]; Hr[tid*4+i] = f2b(v[i]*scale); }
}

__global__ void k_rms_f32(const float* __restrict__ X, bf16* __restrict__ H) {
  int row = blockIdx.x;
  int tid = threadIdx.x;
  const float* xr = X + (size_t)row * DM;
  float v[4]; float ss = 0.f;
  #pragma unroll
  for (int i = 0; i < 4; ++i) { v[i] = xr[tid*4+i]; ss += v[i]*v[i]; }
  __shared__ float red[256];
  red[tid] = ss; __syncthreads();
  for (int s = 128; s > 0; s >>= 1) { if (tid < s) red[tid] += red[tid+s]; __syncthreads(); }
  float scale = rsqrtf(red[0]/(float)DM + 1e-6f);
  bf16* Hr = H + (size_t)row*DM;
  #pragma unroll
  for (int i = 0; i < 4; ++i) Hr[tid*4+i] = f2b(v[i]*scale);
}

// ---------------- weight cast + transpose: Wt[n][k] = bf16(W[k][n]) ----------
__global__ void k_tcast(const float* __restrict__ W, bf16* __restrict__ Wt,
                        int K, int N) {
  __shared__ float t[32][33];
  int tx = threadIdx.x, ty = threadIdx.y;
  int n0 = blockIdx.x*32, k0 = blockIdx.y*32;
  #pragma unroll
  for (int i = 0; i < 4; ++i) {
    int k = k0 + ty + i*8, n = n0 + tx;
    t[ty + i*8][tx] = (n < N) ? W[(size_t)k*N + n] : 0.f;
  }
  __syncthreads();
  #pragma unroll
  for (int i = 0; i < 4; ++i) {
    int n = n0 + ty + i*8, k = k0 + tx;
    Wt[(size_t)n*K + k] = f2b(t[tx][ty + i*8]);
  }
}

// ---------------- MFMA GEMM: C[M,N] = epi(A[M,K] @ Bt[N,K]^T) ----------------
template<int EPI, bool ADD, bool OUTBF>
__global__ __launch_bounds__(256)
void mfma_gemm(const bf16* __restrict__ A, const bf16* __restrict__ Bt,
               float* __restrict__ C, bf16* __restrict__ Cbf,
               int M, int N, int K) {
  __shared__ bf16 As[128*32];
  __shared__ bf16 Bs[128*32];
  int tid = threadIdx.x;
  int wave = tid >> 6, lane = tid & 63;
  int m_l = lane & 15, quad = lane >> 4;
  int wr = (wave & 1) * 64, wc = (wave >> 1) * 64;
  int row0 = blockIdx.y * 128, col0 = blockIdx.x * 128;
  f32x4 acc[4][4];
  #pragma unroll
  for (int i = 0; i < 4; ++i)
    #pragma unroll
    for (int j = 0; j < 4; ++j) acc[i][j] = (f32x4){0.f,0.f,0.f,0.f};
  int r_a = tid >> 2;            // 0..63
  int kc  = (tid & 3) * 8;       // 0,8,16,24
  for (int k0 = 0; k0 < K; k0 += 32) {
    uint4 av0 = *(const uint4*)&A [(size_t)(row0      + r_a) * K + k0 + kc];
    uint4 av1 = *(const uint4*)&A [(size_t)(row0 + 64 + r_a) * K + k0 + kc];
    uint4 bv0 = *(const uint4*)&Bt[(size_t)(col0      + r_a) * K + k0 + kc];
    uint4 bv1 = *(const uint4*)&Bt[(size_t)(col0 + 64 + r_a) * K + k0 + kc];
    __syncthreads();
    *(uint4*)&As[(     r_a) * 32 + kc] = av0;
    *(uint4*)&As[(64 + r_a) * 32 + kc] = av1;
    *(uint4*)&Bs[(     r_a) * 32 + kc] = bv0;
    *(uint4*)&Bs[(64 + r_a) * 32 + kc] = bv1;
    __syncthreads();
    bf16x8 af[4], bfv[4];
    #pragma unroll
    for (int i = 0; i < 4; ++i) af[i]  = *(const bf16x8*)&As[(wr + i*16 + m_l)*32 + quad*8];
    #pragma unroll
    for (int j = 0; j < 4; ++j) bfv[j] = *(const bf16x8*)&Bs[(wc + j*16 + m_l)*32 + quad*8];
    #pragma unroll
    for (int i = 0; i < 4; ++i)
      #pragma unroll
      for (int j = 0; j < 4; ++j)
        acc[i][j] = __builtin_amdgcn_mfma_f32_16x16x32_bf16(af[i], bfv[j], acc[i][j], 0, 0, 0);
  }
  #pragma unroll
  for (int i = 0; i < 4; ++i) {
    #pragma unroll
    for (int j = 0; j < 4; ++j) {
      int col = col0 + wc + j*16 + m_l;
      if (col < N) {
        #pragma unroll
        for (int r = 0; r < 4; ++r) {
          int row = row0 + wr + i*16 + quad*4 + r;
          float v = acc[i][j][r];
          if (EPI == 1) { v = fmaxf(v, 0.f); v = v*v; }          // relu^2
          else if (EPI == 2) v = 1.f/(1.f + __expf(-v));          // sigmoid
          if (OUTBF)      Cbf[(size_t)row*N + col] = f2b(v);
          else if (ADD)   C[(size_t)row*N + col] += v;
          else            C[(size_t)row*N + col]  = v;
        }
      }
    }
  }
}

// ---------------- SSM conv (K=4) + silu + dt softplus ------------------------
// Reads raw gemm-out XBCD_raw[bt][0..2336): xBC at [0,2304), dt at [2304,2336)
__global__ void k_conv_ssm(const float* __restrict__ ZXr, const float* __restrict__ cw,
                           const float* __restrict__ cb, const float* __restrict__ dtb,
                           float* __restrict__ XBC, float* __restrict__ DT) {
  int bt = blockIdx.x; int b = bt >> 10; int t = bt & 1023;
  int tid = threadIdx.x;
  for (int c = tid; c < NXBC; c += 256) {
    float acc = cb[c];
    #pragma unroll
    for (int kk = 0; kk < 4; ++kk) {
      int ts = t - 3 + kk;
      if (ts >= 0) acc += cw[c*4+kk] * ZXr[((size_t)(b*TT+ts))*NXBCD + c];
    }
    float s = acc / (1.f + __expf(-acc));  // silu
    XBC[(size_t)bt*NXBC + c] = s;
  }
  if (tid < NHS) {
    float x = ZXr[(size_t)bt*NXBCD + NXBC + tid] + dtb[tid];
    float sp = (x > 20.f) ? x : log1pf(__expf(x));
    DT[(size_t)bt*NHS + tid] = sp;
  }
}

// ---------------- scan pass 1: intra-chunk (zero-init state) -----------------
// grid 512 = bh*8 + c; 512 threads. Writes partial Y, SC[bh][c][p][n], CUM.
__global__ __launch_bounds__(512)
void k_scan1(const float* __restrict__ xbc, const float* __restrict__ dt,
             const float* __restrict__ A_log, const float* __restrict__ Dmv,
             float* __restrict__ Y, float* __restrict__ SC, float* __restrict__ CUM) {
  int bc = blockIdx.x;
  int bh = bc >> 3, c = bc & 7;
  int b = bh >> 5, h = bh & 31;
  int tid = threadIdx.x;
  int p = tid >> 3, g = tid & 7;
  float A = -__expf(A_log[h]);
  float Dmh = Dmv[h];
  __shared__ float sB[8][128], sCc[8][128], sx[8][64], sdt[8];
  float st[16];
  #pragma unroll
  for (int j = 0; j < 16; ++j) st[j] = 0.f;
  float cp = 1.f;
  int t0 = c * CL;
  for (int tb = 0; tb < CL; tb += 8) {
    for (int e = tid; e < 8*321; e += 512) {
      int tt = e / 321, r = e - 321*tt;
      int t = t0 + tb + tt;
      const float* row = xbc + (size_t)(b*TT + t) * NXBC;
      if (r < 128)       sB[tt][r]        = row[2048 + r];
      else if (r < 256)  sCc[tt][r - 128] = row[2176 + (r - 128)];
      else if (r < 320)  sx[tt][r - 256]  = row[h*64 + (r - 256)];
      else               sdt[tt]          = dt[(size_t)(b*TT + t)*NHS + h];
    }
    __syncthreads();
    #pragma unroll
    for (int tt = 0; tt < 8; ++tt) {
      float dtt = sdt[tt];
      float dA  = __expf(dtt * A);
      cp *= dA;
      float dtx = dtt * sx[tt][p];
      float acc = 0.f;
      #pragma unroll
      for (int j = 0; j < 16; ++j) {
        int n = g*16 + j;
        st[j] = st[j]*dA + dtx*sB[tt][n];
        acc  += st[j]*sCc[tt][n];
      }
      acc += __shfl_xor(acc, 1);
      acc += __shfl_xor(acc, 2);
      acc += __shfl_xor(acc, 4);
      int t = t0 + tb + tt;
      if (g == 0) Y[(size_t)(b*TT + t)*DI + h*64 + p] = acc + sx[tt][p]*Dmh;
      if (tid == 0) CUM[(size_t)bh*TT + t] = cp;
    }
    __syncthreads();
  }
  size_t base = ((size_t)(bh*NC + c)*64 + p)*128 + g*16;
  #pragma unroll
  for (int j = 0; j < 16; ++j) SC[base + j] = st[j];
}

// ---------------- scan pass 2: sequential inter-chunk combine ----------------
// grid 64 (bh); 512 threads; rewrites SC[c] in place with S_init at chunk c.
__global__ __launch_bounds__(512)
void k_scan2(float* __restrict__ SC, const float* __restrict__ CUM) {
  int bh = blockIdx.x;
  int tid = threadIdx.x;
  int p = tid >> 3, g = tid & 7;
  float S[16];
  #pragma unroll
  for (int j = 0; j < 16; ++j) S[j] = 0.f;
  for (int c = 0; c < NC; ++c) {
    size_t base = ((size_t)(bh*NC + c)*64 + p)*128 + g*16;
    float Ptot = CUM[(size_t)bh*TT + c*CL + (CL-1)];
    float tmp[16];
    #pragma unroll
    for (int j = 0; j < 16; ++j) tmp[j] = SC[base + j];
    #pragma unroll
    for (int j = 0; j < 16; ++j) SC[base + j] = S[j];
    #pragma unroll
    for (int j = 0; j < 16; ++j) S[j] = S[j]*Ptot + tmp[j];
  }
}

// ---------------- scan pass 3: fixup Y += CUM[t] * (S_init @ C_t) ------------
// grid 512 = bh*8 + c (c==0 exits); 512 threads.
__global__ __launch_bounds__(512)
void k_scan3(const float* __restrict__ xbc, const float* __restrict__ SC,
             const float* __restrict__ CUM, float* __restrict__ Y) {
  int bc = blockIdx.x;
  int bh = bc >> 3, c = bc & 7;
  if (c == 0) return;
  int b = bh >> 5, h = bh & 31;
  int tid = threadIdx.x;
  int p = tid >> 3, g = tid & 7;
  float S[16];
  size_t base = ((size_t)(bh*NC + c)*64 + p)*128 + g*16;
  #pragma unroll
  for (int j = 0; j < 16; ++j) S[j] = SC[base + j];
  __shared__ float sCc[8][128];
  __shared__ float scp[8];
  int t0 = c * CL;
  for (int tb = 0; tb < CL; tb += 8) {
    for (int e = tid; e < 8*129; e += 512) {
      int tt = e / 129, r = e - 129*tt;
      int t = t0 + tb + tt;
      if (r < 128) sCc[tt][r] = xbc[(size_t)(b*TT + t)*NXBC + 2176 + r];
      else         scp[tt]    = CUM[(size_t)bh*TT + t];
    }
    __syncthreads();
    #pragma unroll
    for (int tt = 0; tt < 8; ++tt) {
      float acc = 0.f;
      #pragma unroll
      for (int j = 0; j < 16; ++j) acc += S[j]*sCc[tt][g*16 + j];
      acc += __shfl_xor(acc, 1);
      acc += __shfl_xor(acc, 2);
      acc += __shfl_xor(acc, 4);
      if (g == 0) {
        int t = t0 + tb + tt;
        size_t yi = (size_t)(b*TT + t)*DI + h*64 + p;
        Y[yi] += scp[tt]*acc;
      }
    }
    __syncthreads();
  }
}

// ---------------- gate: Ybf = bf16(rmsnorm(y * silu(z)) * mnorm_w) -----------
__global__ void k_gate(const float* __restrict__ Y, const float* __restrict__ Z,
                       const float* __restrict__ mnw, bf16* __restrict__ Ybf) {
  int row = blockIdx.x; int tid = threadIdx.x;  // 256 thr, 8 elems each (DI=2048)
  const float* yr = Y + (size_t)row*DI;
  const float* zr = Z + (size_t)row*DI;
  float gv[8]; float ss = 0.f;
  #pragma unroll
  for (int i = 0; i < 8; ++i) {
    int c = tid*8 + i;
    float z = zr[c];
    float sz = z / (1.f + __expf(-z));
    float v = yr[c]*sz;
    gv[i] = v; ss += v*v;
  }
  __shared__ float red[256];
  red[tid] = ss; __syncthreads();
  for (int s = 128; s > 0; s >>= 1) { if (tid < s) red[tid] += red[tid+s]; __syncthreads(); }
  float scale = rsqrtf(red[0]/(float)DI + 1e-5f);
  bf16* br = Ybf + (size_t)row*DI;
  #pragma unroll
  for (int i = 0; i < 8; ++i) { int c = tid*8 + i; br[c] = f2b(gv[i]*scale*mnw[c]); }
}

// ---------------- q/k/v causal dwconv (K=3) ----------------------------------
__global__ void k_conv_qkv(const float* __restrict__ QKV,
                           const float* qw, const float* qb, const float* kw, const float* kb,
                           const float* vw, const float* vb,
                           float* __restrict__ Q, float* __restrict__ Kc, float* __restrict__ Vc) {
  int bt = blockIdx.x; int b = bt >> 10; int t = bt & 1023;
  int tid = threadIdx.x;
  for (int c = tid; c < 1152; c += 256) {
    if (c < 1024) {
      int h = c >> 6, d = c & 63;
      float acc = qb[d];
      #pragma unroll
      for (int kk = 0; kk < 3; ++kk) { int ts = t-2+kk; if (ts >= 0) acc += qw[d*3+kk] * QKV[((size_t)(b*TT+ts))*1152 + c]; }
      Q[((size_t)(b*NHA + h)*TT + t)*HD + d] = acc;
    } else if (c < 1088) {
      int d = c - 1024;
      float acc = kb[d];
      #pragma unroll
      for (int kk = 0; kk < 3; ++kk) { int ts = t-2+kk; if (ts >= 0) acc += kw[d*3+kk] * QKV[((size_t)(b*TT+ts))*1152 + c]; }
      Kc[(size_t)bt*HD + d] = acc;
    } else {
      int d = c - 1088;
      float acc = vb[d];
      #pragma unroll
      for (int kk = 0; kk < 3; ++kk) { int ts = t-2+kk; if (ts >= 0) acc += vw[d*3+kk] * QKV[((size_t)(b*TT+ts))*1152 + c]; }
      Vc[(size_t)bt*HD + d] = acc;
    }
  }
}

// ---------------- attention: 1 wave per (b,h,t), online softmax, bf16 out ----
__global__ void k_attn(const float* __restrict__ Q, const float* __restrict__ Kc,
                       const float* __restrict__ Vc, bf16* __restrict__ out) {
  int t = blockIdx.x, h = blockIdx.y, b = blockIdx.z;
  int lane = threadIdx.x;  // 64
  __shared__ float qs[64], ps[64];
  qs[lane] = Q[((size_t)(b*NHA + h)*TT + t)*HD + lane] * 0.125f;  // 1/sqrt(64)
  __syncthreads();
  float m = -INFINITY, l = 0.f, o = 0.f;
  for (int s0 = 0; s0 <= t; s0 += 64) {
    int s = s0 + lane;
    float score = -INFINITY;
    if (s <= t) {
      float acc = 0.f;
      const float* kr = &Kc[(size_t)(b*TT + s)*HD];
      #pragma unroll
      for (int d = 0; d < 64; ++d) acc += qs[d]*kr[d];
      score = acc;
    }
    float tm = score;
    #pragma unroll
    for (int off = 32; off; off >>= 1) tm = fmaxf(tm, __shfl_xor(tm, off));
    float newm = fmaxf(m, tm);
    float p = (s <= t) ? __expf(score - newm) : 0.f;
    float tsum = p;
    #pragma unroll
    for (int off = 32; off; off >>= 1) tsum += __shfl_xor(tsum, off);
    float alpha = __expf(m - newm);
    l = l*alpha + tsum;
    m = newm;
    ps[lane] = p;
    __syncthreads();
    float oacc = 0.f;
    int smax = min(63, t - s0);
    for (int ss = 0; ss <= smax; ++ss)
      oacc += ps[ss] * Vc[(size_t)(b*TT + s0 + ss)*HD + lane];
    o = o*alpha + oacc;
    __syncthreads();
  }
  out[(size_t)(b*TT + t)*DM + h*HD + lane] = f2b(o / l);
}

// ---------------- token shift (bf16 in/out) ----------------------------------
__global__ void k_tshift(const bf16* __restrict__ H, const float* __restrict__ maak,
                         const float* __restrict__ maar,
                         bf16* __restrict__ XK, bf16* __restrict__ XR) {
  int idx = blockIdx.x*256 + threadIdx.x;   // B*T*DM total
  int c = idx & (DM - 1);
  int bt = idx >> 10;
  int t = bt & (TT - 1);
  float h = b2f(H[idx]);
  float prev = (t > 0) ? b2f(H[idx - DM]) : 0.f;
  float xx = prev - h;
  XK[idx] = f2b(h + xx*maak[c]);
  XR[idx] = f2b(h + xx*maar[c]);
}

// ---------------- final: out = x + sigmoid_r * kv ----------------------------
__global__ void k_final(const float* __restrict__ X, const float* __restrict__ R,
                        const float* __restrict__ KV, float* __restrict__ out) {
  int idx = blockIdx.x*256 + threadIdx.x;
  out[idx] = X[idx] + R[idx]*KV[idx];
}

// =============================================================================
extern "C" void kernel_launch(void* const* d_in, const int* in_sizes, int n_in,
                              void* d_out, int out_size, void* d_ws, size_t ws_size,
                              hipStream_t stream) {
  const float* x_in    = (const float*)d_in[0];
  const float* W_in    = (const float*)d_in[1];
  const float* conv_w  = (const float*)d_in[2];
  const float* conv_b  = (const float*)d_in[3];
  const float* A_log   = (const float*)d_in[4];
  const float* Dm      = (const float*)d_in[5];
  const float* dt_bias = (const float*)d_in[6];
  const float* mnorm_w = (const float*)d_in[7];
  const float* W_out   = (const float*)d_in[8];
  const float* W_qkv   = (const float*)d_in[9];
  const float* W_cproj = (const float*)d_in[10];
  const float* qconv_w = (const float*)d_in[11];
  const float* qconv_b = (const float*)d_in[12];
  const float* kconv_w = (const float*)d_in[13];
  const float* kconv_b = (const float*)d_in[14];
  const float* vconv_w = (const float*)d_in[15];
  const float* vconv_b = (const float*)d_in[16];
  const float* maa_k   = (const float*)d_in[17];
  const float* maa_r   = (const float*)d_in[18];
  const float* W_key   = (const float*)d_in[19];
  const float* W_rec   = (const float*)d_in[20];
  const float* W_val   = (const float*)d_in[21];
  float* out = (float*)d_out;

  float* ws = (float*)d_ws;
  // persistent regions (float-unit offsets), total 21,168,128 fl = 84.7 MB
  float* X       = ws;                       // [0, 2,097,152)
  bf16*  Hbf     = (bf16*)(ws + 2097152);    // 2,097,152 bf16
  float* Zbuf    = ws + 3145728;             // [.., +4,194,304)   z half of W_in out
  float* XBCDraw = ws + 7340032;             // [.., +4,784,128)   xBC+dt raw gemm out
  float* XBC     = ws + 12124160;            // [.., +4,718,592)   conv output
  float* DT      = ws + 16842752;            // [.., +65,536)
  float* CUM     = ws + 16908288;            // [.., +65,536)
  float* Y       = ws + 16973824;            // [.., +4,194,304)

  // lifetime-disjoint aliases
  bf16*  Wt_in    = (bf16*)XBC;              // step 2   (4480x1024 bf16)
  float* SC       = XBCDraw;                 // scan chunk states (4,194,304 fl)
  bf16*  Ybf      = (bf16*)XBC;              // steps 5-6 (2048x2048 bf16)
  bf16*  Wt_out   = (bf16*)(XBC + 2097152);  // step 6   (1024x2048 bf16)
  float* QKV      = Zbuf;                    // steps 8-9 (2048x1152)
  bf16*  Wt_qkv   = (bf16*)XBC;              // step 8   (1152x1024 bf16)
  float* Q        = XBCDraw;                 // steps 9-10 (2048x1024)
  float* Kc       = XBCDraw + 2097152;       // 2048x64
  float* Vc       = XBCDraw + 2228224;       // 2048x64
  bf16*  ATTNbf   = (bf16*)Y;                // steps 10-11 (2048x1024 bf16)
  bf16*  Wt_cproj = (bf16*)(Y + 1048576);    // step 11  (1024x1024 bf16)
  bf16*  XKbf     = (bf16*)XBC;              // steps 13-14 (2048x1024 bf16)
  bf16*  XRbf     = (bf16*)(XBC + 1048576);  // steps 13,16 (2048x1024 bf16)
  bf16*  Wt_key   = (bf16*)Zbuf;             // step 14  (4096x1024 bf16)
  bf16*  KFbf     = (bf16*)XBCDraw;          // steps 14-15 (2048x4096 bf16)
  bf16*  Wt_val   = (bf16*)Zbuf;             // step 15  (1024x4096 bf16)
  float* KV       = Y;                       // steps 15-17 (2048x1024)
  float* R        = Y + 2097152;             // steps 16-17 (2048x1024)
  bf16*  Wt_rec   = (bf16*)Zbuf;             // step 16  (1024x1024 bf16)

  dim3 thr256(256), thr64(64), thr512(512);
  dim3 tblk(32, 8);

  // 1. X = x; Hbf = rmsnorm(x)
  k_rms_in<<<BT, thr256, 0, stream>>>(x_in, X, Hbf);
  // 2. [Z | XBCDraw] = Hbf @ W_in  (split output; N padded to 4480 in Wt)
  k_tcast<<<dim3(4480/32, 1024/32), tblk, 0, stream>>>(W_in, Wt_in, 1024, NZX);
  mfma_gemm<0,false,false><<<dim3(2048/128, BT/128), thr256, 0, stream>>>(Hbf, Wt_in, Zbuf, nullptr, BT, 2048, 1024);
  mfma_gemm<0,false,false><<<dim3(19, BT/128), thr256, 0, stream>>>(Hbf, Wt_in + (size_t)2048*1024, XBCDraw, nullptr, BT, NXBCD, 1024);
  // 3. conv+silu on xBC, softplus dt
  k_conv_ssm<<<BT, thr256, 0, stream>>>(XBCDraw, conv_w, conv_b, dt_bias, XBC, DT);
  // 4. SSM chunked scan (SC aliases XBCDraw — dead after conv)
  k_scan1<<<BB*NHS*NC, thr512, 0, stream>>>(XBC, DT, A_log, Dm, Y, SC, CUM);
  k_scan2<<<BB*NHS, thr512, 0, stream>>>(SC, CUM);
  k_scan3<<<BB*NHS*NC, thr512, 0, stream>>>(XBC, SC, CUM, Y);
  // 5. gate + mnorm -> Ybf
  k_gate<<<BT, thr256, 0, stream>>>(Y, Zbuf, mnorm_w, Ybf);
  // 6. X += Ybf @ W_out  [2048,2048]x[2048,1024]
  k_tcast<<<dim3(1024/32, 2048/32), tblk, 0, stream>>>(W_out, Wt_out, 2048, 1024);
  mfma_gemm<0,true,false><<<dim3(1024/128, BT/128), thr256, 0, stream>>>(Ybf, Wt_out, X, nullptr, BT, 1024, 2048);
  // 7. Hbf = rmsnorm(X)
  k_rms_f32<<<BT, thr256, 0, stream>>>(X, Hbf);
  // 8. QKV = Hbf @ W_qkv  [2048,1024]x[1024,1152]
  k_tcast<<<dim3(1152/32, 1024/32), tblk, 0, stream>>>(W_qkv, Wt_qkv, 1024, 1152);
  mfma_gemm<0,false,false><<<dim3(1152/128, BT/128), thr256, 0, stream>>>(Hbf, Wt_qkv, QKV, nullptr, BT, 1152, 1024);
  // 9. q/k/v convs
  k_conv_qkv<<<BT, thr256, 0, stream>>>(QKV, qconv_w, qconv_b, kconv_w, kconv_b, vconv_w, vconv_b, Q, Kc, Vc);
  // 10. attention -> ATTNbf
  k_attn<<<dim3(TT, NHA, BB), thr64, 0, stream>>>(Q, Kc, Vc, ATTNbf);
  // 11. X += ATTNbf @ W_cproj
  k_tcast<<<dim3(1024/32, 1024/32), tblk, 0, stream>>>(W_cproj, Wt_cproj, 1024, 1024);
  mfma_gemm<0,true,false><<<dim3(1024/128, BT/128), thr256, 0, stream>>>(ATTNbf, Wt_cproj, X, nullptr, BT, 1024, 1024);
  // 12. Hbf = rmsnorm(X)
  k_rms_f32<<<BT, thr256, 0, stream>>>(X, Hbf);
  // 13. token shift -> XKbf, XRbf
  k_tshift<<<(BT*DM)/256, thr256, 0, stream>>>(Hbf, maa_k, maa_r, XKbf, XRbf);
  // 14. KFbf = bf16(relu(XKbf @ W_key)^2)  [2048,1024]x[1024,4096]
  k_tcast<<<dim3(4096/32, 1024/32), tblk, 0, stream>>>(W_key, Wt_key, 1024, 4096);
  mfma_gemm<1,false,true><<<dim3(4096/128, BT/128), thr256, 0, stream>>>(XKbf, Wt_key, nullptr, KFbf, BT, 4096, 1024);
  // 15. KV = KFbf @ W_val  [2048,4096]x[4096,1024]
  k_tcast<<<dim3(1024/32, 4096/32), tblk, 0, stream>>>(W_val, Wt_val, 4096, 1024);
  mfma_gemm<0,false,false><<<dim3(1024/128, BT/128), thr256, 0, stream>>>(KFbf, Wt_val, KV, nullptr, BT, 1024, 4096);
  // 16. R = sigmoid(XRbf @ W_rec)
  k_tcast<<<dim3(1024/32, 1024/32), tblk, 0, stream>>>(W_rec, Wt_rec, 1024, 1024);
  mfma_gemm<2,false,false><<<dim3(1024/128, BT/128), thr256, 0, stream>>>(XRbf, Wt_rec, R, nullptr, BT, 1024, 1024);
  // 17. out = x + sigmoid_r * kv
  k_final<<<(BT*DM)/256, thr256, 0, stream>>>(X, R, KV, out);
}

// Round 5
// 818.828 us; speedup vs baseline: 5.3524x; 1.6793x over previous
//
#include <hip/hip_runtime.h>
#include <hip/hip_bf16.h>
#include <math.h>

#define BB 2
#define TT 1024
#define BT (BB*TT)          // 2048 rows
#define DM 1024
#define DI 2048
#define DS 128
#define NHS 32              // ssm heads
#define PDIM 64             // ssm headdim
#define NHA 16              // attn heads
#define HD 64
#define FFN_ 4096
#define NZX 4384            // 2*DI + 2*DS + NHS
#define NXBC 2304           // DI + 2*DS
#define NXBCD 2336          // xBC (2304) + dt (32) raw gemm-out width
#define CL 128              // scan chunk length
#define NC 8                // chunks

typedef __hip_bfloat16 bf16;
typedef short bf16x8 __attribute__((ext_vector_type(8)));
typedef float f32x4 __attribute__((ext_vector_type(4)));

__device__ __forceinline__ float b2f(bf16 v){ return __bfloat162float(v); }
__device__ __forceinline__ bf16 f2b(float v){ return __float2bfloat16(v); }

// ---------------- RMSNorm: write fp32 X copy + bf16 normalized H -------------
__global__ void k_rms_in(const float* __restrict__ xin, float* __restrict__ X,
                         bf16* __restrict__ H) {
  int row = blockIdx.x;
  int tid = threadIdx.x;          // 256 threads, 4 elems each (DM=1024)
  const float* xr = xin + (size_t)row * DM;
  float v[4]; float ss = 0.f;
  #pragma unroll
  for (int i = 0; i < 4; ++i) { v[i] = xr[tid*4+i]; ss += v[i]*v[i]; }
  __shared__ float red[256];
  red[tid] = ss; __syncthreads();
  for (int s = 128; s > 0; s >>= 1) { if (tid < s) red[tid] += red[tid+s]; __syncthreads(); }
  float scale = rsqrtf(red[0]/(float)DM + 1e-6f);
  float* Xr = X + (size_t)row*DM; bf16* Hr = H + (size_t)row*DM;
  #pragma unroll
  for (int i = 0; i < 4; ++i) { Xr[tid*4+i] = v[i]; Hr[tid*4+i] = f2b(v[i]*scale); }
}

__global__ void k_rms_f32(const float* __restrict__ X, bf16* __restrict__ H) {
  int row = blockIdx.x;
  int tid = threadIdx.x;
  const float* xr = X + (size_t)row * DM;
  float v[4]; float ss = 0.f;
  #pragma unroll
  for (int i = 0; i < 4; ++i) { v[i] = xr[tid*4+i]; ss += v[i]*v[i]; }
  __shared__ float red[256];
  red[tid] = ss; __syncthreads();
  for (int s = 128; s > 0; s >>= 1) { if (tid < s) red[tid] += red[tid+s]; __syncthreads(); }
  float scale = rsqrtf(red[0]/(float)DM + 1e-6f);
  bf16* Hr = H + (size_t)row*DM;
  #pragma unroll
  for (int i = 0; i < 4; ++i) Hr[tid*4+i] = f2b(v[i]*scale);
}

// ---------------- weight cast + transpose: Wt[n][k] = bf16(W[k][n]) ----------
__global__ void k_tcast(const float* __restrict__ W, bf16* __restrict__ Wt,
                        int K, int N) {
  __shared__ float t[32][33];
  int tx = threadIdx.x, ty = threadIdx.y;
  int n0 = blockIdx.x*32, k0 = blockIdx.y*32;
  #pragma unroll
  for (int i = 0; i < 4; ++i) {
    int k = k0 + ty + i*8, n = n0 + tx;
    t[ty + i*8][tx] = (n < N) ? W[(size_t)k*N + n] : 0.f;
  }
  __syncthreads();
  #pragma unroll
  for (int i = 0; i < 4; ++i) {
    int n = n0 + ty + i*8, k = k0 + tx;
    Wt[(size_t)n*K + k] = f2b(t[tx][ty + i*8]);
  }
}

// ---------------- MFMA GEMM: C[M,N] = epi(A[M,K] @ Bt[N,K]^T) ----------------
template<int EPI, bool ADD, bool OUTBF>
__global__ __launch_bounds__(256)
void mfma_gemm(const bf16* __restrict__ A, const bf16* __restrict__ Bt,
               float* __restrict__ C, bf16* __restrict__ Cbf,
               int M, int N, int K) {
  __shared__ bf16 As[128*32];
  __shared__ bf16 Bs[128*32];
  int tid = threadIdx.x;
  int wave = tid >> 6, lane = tid & 63;
  int m_l = lane & 15, quad = lane >> 4;
  int wr = (wave & 1) * 64, wc = (wave >> 1) * 64;
  int row0 = blockIdx.y * 128, col0 = blockIdx.x * 128;
  f32x4 acc[4][4];
  #pragma unroll
  for (int i = 0; i < 4; ++i)
    #pragma unroll
    for (int j = 0; j < 4; ++j) acc[i][j] = (f32x4){0.f,0.f,0.f,0.f};
  int r_a = tid >> 2;            // 0..63
  int kc  = (tid & 3) * 8;       // 0,8,16,24
  for (int k0 = 0; k0 < K; k0 += 32) {
    uint4 av0 = *(const uint4*)&A [(size_t)(row0      + r_a) * K + k0 + kc];
    uint4 av1 = *(const uint4*)&A [(size_t)(row0 + 64 + r_a) * K + k0 + kc];
    uint4 bv0 = *(const uint4*)&Bt[(size_t)(col0      + r_a) * K + k0 + kc];
    uint4 bv1 = *(const uint4*)&Bt[(size_t)(col0 + 64 + r_a) * K + k0 + kc];
    __syncthreads();
    *(uint4*)&As[(     r_a) * 32 + kc] = av0;
    *(uint4*)&As[(64 + r_a) * 32 + kc] = av1;
    *(uint4*)&Bs[(     r_a) * 32 + kc] = bv0;
    *(uint4*)&Bs[(64 + r_a) * 32 + kc] = bv1;
    __syncthreads();
    bf16x8 af[4], bfv[4];
    #pragma unroll
    for (int i = 0; i < 4; ++i) af[i]  = *(const bf16x8*)&As[(wr + i*16 + m_l)*32 + quad*8];
    #pragma unroll
    for (int j = 0; j < 4; ++j) bfv[j] = *(const bf16x8*)&Bs[(wc + j*16 + m_l)*32 + quad*8];
    #pragma unroll
    for (int i = 0; i < 4; ++i)
      #pragma unroll
      for (int j = 0; j < 4; ++j)
        acc[i][j] = __builtin_amdgcn_mfma_f32_16x16x32_bf16(af[i], bfv[j], acc[i][j], 0, 0, 0);
  }
  #pragma unroll
  for (int i = 0; i < 4; ++i) {
    #pragma unroll
    for (int j = 0; j < 4; ++j) {
      int col = col0 + wc + j*16 + m_l;
      if (col < N) {
        #pragma unroll
        for (int r = 0; r < 4; ++r) {
          int row = row0 + wr + i*16 + quad*4 + r;
          float v = acc[i][j][r];
          if (EPI == 1) { v = fmaxf(v, 0.f); v = v*v; }          // relu^2
          else if (EPI == 2) v = 1.f/(1.f + __expf(-v));          // sigmoid
          if (OUTBF)      Cbf[(size_t)row*N + col] = f2b(v);
          else if (ADD)   C[(size_t)row*N + col] += v;
          else            C[(size_t)row*N + col]  = v;
        }
      }
    }
  }
}

// ---------------- SSM conv (K=4) + silu + dt softplus ------------------------
__global__ void k_conv_ssm(const float* __restrict__ ZXr, const float* __restrict__ cw,
                           const float* __restrict__ cb, const float* __restrict__ dtb,
                           float* __restrict__ XBC, float* __restrict__ DT) {
  int bt = blockIdx.x; int b = bt >> 10; int t = bt & 1023;
  int tid = threadIdx.x;
  for (int c = tid; c < NXBC; c += 256) {
    float acc = cb[c];
    #pragma unroll
    for (int kk = 0; kk < 4; ++kk) {
      int ts = t - 3 + kk;
      if (ts >= 0) acc += cw[c*4+kk] * ZXr[((size_t)(b*TT+ts))*NXBCD + c];
    }
    float s = acc / (1.f + __expf(-acc));  // silu
    XBC[(size_t)bt*NXBC + c] = s;
  }
  if (tid < NHS) {
    float x = ZXr[(size_t)bt*NXBCD + NXBC + tid] + dtb[tid];
    float sp = (x > 20.f) ? x : log1pf(__expf(x));
    DT[(size_t)bt*NHS + tid] = sp;
  }
}

// ---------------- scan pass 1: intra-chunk (zero-init state) -----------------
__global__ __launch_bounds__(512)
void k_scan1(const float* __restrict__ xbc, const float* __restrict__ dt,
             const float* __restrict__ A_log, const float* __restrict__ Dmv,
             float* __restrict__ Y, float* __restrict__ SC, float* __restrict__ CUM) {
  int bc = blockIdx.x;
  int bh = bc >> 3, c = bc & 7;
  int b = bh >> 5, h = bh & 31;
  int tid = threadIdx.x;
  int p = tid >> 3, g = tid & 7;
  float A = -__expf(A_log[h]);
  float Dmh = Dmv[h];
  __shared__ float sB[8][128], sCc[8][128], sx[8][64], sdt[8];
  float st[16];
  #pragma unroll
  for (int j = 0; j < 16; ++j) st[j] = 0.f;
  float cp = 1.f;
  int t0 = c * CL;
  for (int tb = 0; tb < CL; tb += 8) {
    for (int e = tid; e < 8*321; e += 512) {
      int tt = e / 321, r = e - 321*tt;
      int t = t0 + tb + tt;
      const float* row = xbc + (size_t)(b*TT + t) * NXBC;
      if (r < 128)       sB[tt][r]        = row[2048 + r];
      else if (r < 256)  sCc[tt][r - 128] = row[2176 + (r - 128)];
      else if (r < 320)  sx[tt][r - 256]  = row[h*64 + (r - 256)];
      else               sdt[tt]          = dt[(size_t)(b*TT + t)*NHS + h];
    }
    __syncthreads();
    #pragma unroll
    for (int tt = 0; tt < 8; ++tt) {
      float dtt = sdt[tt];
      float dA  = __expf(dtt * A);
      cp *= dA;
      float dtx = dtt * sx[tt][p];
      float acc = 0.f;
      #pragma unroll
      for (int j = 0; j < 16; ++j) {
        int n = g*16 + j;
        st[j] = st[j]*dA + dtx*sB[tt][n];
        acc  += st[j]*sCc[tt][n];
      }
      acc += __shfl_xor(acc, 1);
      acc += __shfl_xor(acc, 2);
      acc += __shfl_xor(acc, 4);
      int t = t0 + tb + tt;
      if (g == 0) Y[(size_t)(b*TT + t)*DI + h*64 + p] = acc + sx[tt][p]*Dmh;
      if (tid == 0) CUM[(size_t)bh*TT + t] = cp;
    }
    __syncthreads();
  }
  size_t base = ((size_t)(bh*NC + c)*64 + p)*128 + g*16;
  #pragma unroll
  for (int j = 0; j < 16; ++j) SC[base + j] = st[j];
}

// ---------------- scan pass 2: sequential inter-chunk combine ----------------
__global__ __launch_bounds__(512)
void k_scan2(float* __restrict__ SC, const float* __restrict__ CUM) {
  int bh = blockIdx.x;
  int tid = threadIdx.x;
  int p = tid >> 3, g = tid & 7;
  float S[16];
  #pragma unroll
  for (int j = 0; j < 16; ++j) S[j] = 0.f;
  for (int c = 0; c < NC; ++c) {
    size_t base = ((size_t)(bh*NC + c)*64 + p)*128 + g*16;
    float Ptot = CUM[(size_t)bh*TT + c*CL + (CL-1)];
    float tmp[16];
    #pragma unroll
    for (int j = 0; j < 16; ++j) tmp[j] = SC[base + j];
    #pragma unroll
    for (int j = 0; j < 16; ++j) SC[base + j] = S[j];
    #pragma unroll
    for (int j = 0; j < 16; ++j) S[j] = S[j]*Ptot + tmp[j];
  }
}

// ---------------- scan pass 3: fixup Y += CUM[t] * (S_init @ C_t) ------------
__global__ __launch_bounds__(512)
void k_scan3(const float* __restrict__ xbc, const float* __restrict__ SC,
             const float* __restrict__ CUM, float* __restrict__ Y) {
  int bc = blockIdx.x;
  int bh = bc >> 3, c = bc & 7;
  if (c == 0) return;
  int b = bh >> 5, h = bh & 31;
  int tid = threadIdx.x;
  int p = tid >> 3, g = tid & 7;
  float S[16];
  size_t base = ((size_t)(bh*NC + c)*64 + p)*128 + g*16;
  #pragma unroll
  for (int j = 0; j < 16; ++j) S[j] = SC[base + j];
  __shared__ float sCc[8][128];
  __shared__ float scp[8];
  int t0 = c * CL;
  for (int tb = 0; tb < CL; tb += 8) {
    for (int e = tid; e < 8*129; e += 512) {
      int tt = e / 129, r = e - 129*tt;
      int t = t0 + tb + tt;
      if (r < 128) sCc[tt][r] = xbc[(size_t)(b*TT + t)*NXBC + 2176 + r];
      else         scp[tt]    = CUM[(size_t)bh*TT + t];
    }
    __syncthreads();
    #pragma unroll
    for (int tt = 0; tt < 8; ++tt) {
      float acc = 0.f;
      #pragma unroll
      for (int j = 0; j < 16; ++j) acc += S[j]*sCc[tt][g*16 + j];
      acc += __shfl_xor(acc, 1);
      acc += __shfl_xor(acc, 2);
      acc += __shfl_xor(acc, 4);
      if (g == 0) {
        int t = t0 + tb + tt;
        size_t yi = (size_t)(b*TT + t)*DI + h*64 + p;
        Y[yi] += scp[tt]*acc;
      }
    }
    __syncthreads();
  }
}

// ---------------- gate: Ybf = bf16(rmsnorm(y * silu(z)) * mnorm_w) -----------
__global__ void k_gate(const float* __restrict__ Y, const float* __restrict__ Z,
                       const float* __restrict__ mnw, bf16* __restrict__ Ybf) {
  int row = blockIdx.x; int tid = threadIdx.x;  // 256 thr, 8 elems each (DI=2048)
  const float* yr = Y + (size_t)row*DI;
  const float* zr = Z + (size_t)row*DI;
  float gv[8]; float ss = 0.f;
  #pragma unroll
  for (int i = 0; i < 8; ++i) {
    int c = tid*8 + i;
    float z = zr[c];
    float sz = z / (1.f + __expf(-z));
    float v = yr[c]*sz;
    gv[i] = v; ss += v*v;
  }
  __shared__ float red[256];
  red[tid] = ss; __syncthreads();
  for (int s = 128; s > 0; s >>= 1) { if (tid < s) red[tid] += red[tid+s]; __syncthreads(); }
  float scale = rsqrtf(red[0]/(float)DI + 1e-5f);
  bf16* br = Ybf + (size_t)row*DI;
  #pragma unroll
  for (int i = 0; i < 8; ++i) { int c = tid*8 + i; br[c] = f2b(gv[i]*scale*mnw[c]); }
}

// ---------------- q/k/v causal dwconv (K=3), bf16 out, Q pre-scaled, V^T -----
__global__ void k_conv_qkv(const float* __restrict__ QKV,
                           const float* qw, const float* qb, const float* kw, const float* kb,
                           const float* vw, const float* vb,
                           bf16* __restrict__ Qb, bf16* __restrict__ Kb, bf16* __restrict__ Vtb) {
  int bt = blockIdx.x; int b = bt >> 10; int t = bt & 1023;
  int tid = threadIdx.x;
  for (int c = tid; c < 1152; c += 256) {
    if (c < 1024) {
      int h = c >> 6, d = c & 63;
      float acc = qb[d];
      #pragma unroll
      for (int kk = 0; kk < 3; ++kk) { int ts = t-2+kk; if (ts >= 0) acc += qw[d*3+kk] * QKV[((size_t)(b*TT+ts))*1152 + c]; }
      Qb[((size_t)(b*NHA + h)*TT + t)*HD + d] = f2b(acc * 0.125f);  // 1/sqrt(64)
    } else if (c < 1088) {
      int d = c - 1024;
      float acc = kb[d];
      #pragma unroll
      for (int kk = 0; kk < 3; ++kk) { int ts = t-2+kk; if (ts >= 0) acc += kw[d*3+kk] * QKV[((size_t)(b*TT+ts))*1152 + c]; }
      Kb[(size_t)bt*HD + d] = f2b(acc);
    } else {
      int d = c - 1088;
      float acc = vb[d];
      #pragma unroll
      for (int kk = 0; kk < 3; ++kk) { int ts = t-2+kk; if (ts >= 0) acc += vw[d*3+kk] * QKV[((size_t)(b*TT+ts))*1152 + c]; }
      Vtb[((size_t)(b*HD + d))*TT + t] = f2b(acc);
    }
  }
}

// ---------------- MFMA flash attention ---------------------------------------
// grid (TT/128, NHA, BB), 256 thr = 4 waves; wave owns 32 Q rows.
// Q pre-scaled bf16 [b,h,t,d]; K bf16 [b,t,d]; Vt bf16 [b,d,t]. Causal.
__global__ __launch_bounds__(256)
void k_flash(const bf16* __restrict__ Qb, const bf16* __restrict__ Kb,
             const bf16* __restrict__ Vtb, bf16* __restrict__ out) {
  int qt = blockIdx.x, h = blockIdx.y, b = blockIdx.z;
  int tid = threadIdx.x, wave = tid >> 6, lane = tid & 63;
  int col = lane & 15, quad = lane >> 4;
  int t0 = qt * 128;
  __shared__ bf16 Ks[128*72];     // K rows, padded 64->72
  __shared__ bf16 Vs[64*136];     // V^T rows (d-major), padded 128->136
  __shared__ bf16 Ps[4][32*136];  // per-wave P (A-layout staging)
  // preload Q A-fragments: rows t0+wave*32+i*16+col, k = kf*32+quad*8
  const bf16* Qbase = Qb + ((size_t)(b*NHA + h))*TT*HD;
  bf16x8 qf[2][2];
  #pragma unroll
  for (int i = 0; i < 2; ++i)
    #pragma unroll
    for (int kf = 0; kf < 2; ++kf)
      qf[i][kf] = *(const bf16x8*)&Qbase[(size_t)(t0 + wave*32 + i*16 + col)*HD + kf*32 + quad*8];
  float mst[2][4], lst[2][4];
  f32x4 oacc[2][4];
  #pragma unroll
  for (int i = 0; i < 2; ++i)
    #pragma unroll
    for (int r = 0; r < 4; ++r) { mst[i][r] = -1e30f; lst[i][r] = 0.f; }
  #pragma unroll
  for (int i = 0; i < 2; ++i)
    #pragma unroll
    for (int jd = 0; jd < 4; ++jd) oacc[i][jd] = (f32x4){0.f,0.f,0.f,0.f};

  for (int kt = 0; kt <= qt; ++kt) {
    int s0 = kt * 128;
    __syncthreads();
    // stage K tile (128x64) and Vt tile (64x128)
    for (int e = tid; e < 1024; e += 256) {
      int r = e >> 3, ch = e & 7;
      *(uint4*)&Ks[r*72 + ch*8] = *(const uint4*)&Kb[((size_t)(b*TT + s0 + r))*HD + ch*8];
    }
    for (int e = tid; e < 1024; e += 256) {
      int d = e >> 4, ch = e & 15;
      *(uint4*)&Vs[d*136 + ch*8] = *(const uint4*)&Vtb[((size_t)(b*HD + d))*TT + s0 + ch*8];
    }
    __syncthreads();
    // S = Q K^T  (2 row-tiles x 8 col-tiles)
    f32x4 sacc[2][8];
    #pragma unroll
    for (int i = 0; i < 2; ++i)
      #pragma unroll
      for (int j = 0; j < 8; ++j) sacc[i][j] = (f32x4){0.f,0.f,0.f,0.f};
    #pragma unroll
    for (int j = 0; j < 8; ++j) {
      bf16x8 kf0 = *(const bf16x8*)&Ks[(j*16 + col)*72 + quad*8];
      bf16x8 kf1 = *(const bf16x8*)&Ks[(j*16 + col)*72 + 32 + quad*8];
      #pragma unroll
      for (int i = 0; i < 2; ++i) {
        sacc[i][j] = __builtin_amdgcn_mfma_f32_16x16x32_bf16(qf[i][0], kf0, sacc[i][j], 0, 0, 0);
        sacc[i][j] = __builtin_amdgcn_mfma_f32_16x16x32_bf16(qf[i][1], kf1, sacc[i][j], 0, 0, 0);
      }
    }
    // online softmax (C layout: col=lane&15 -> s, row=quad*4+r -> t)
    bool diag = (kt == qt);
    #pragma unroll
    for (int i = 0; i < 2; ++i) {
      #pragma unroll
      for (int r = 0; r < 4; ++r) {
        int rowloc = wave*32 + i*16 + quad*4 + r;
        if (diag) {
          #pragma unroll
          for (int j = 0; j < 8; ++j)
            if (j*16 + col > rowloc) sacc[i][j][r] = -1e30f;
        }
        float mx = -1e30f;
        #pragma unroll
        for (int j = 0; j < 8; ++j) mx = fmaxf(mx, sacc[i][j][r]);
        mx = fmaxf(mx, __shfl_xor(mx, 1));
        mx = fmaxf(mx, __shfl_xor(mx, 2));
        mx = fmaxf(mx, __shfl_xor(mx, 4));
        mx = fmaxf(mx, __shfl_xor(mx, 8));
        float nm = fmaxf(mst[i][r], mx);
        float alpha = __expf(mst[i][r] - nm);
        float sum = 0.f;
        #pragma unroll
        for (int j = 0; j < 8; ++j) {
          float pv = __expf(sacc[i][j][r] - nm);
          sacc[i][j][r] = pv; sum += pv;
        }
        sum += __shfl_xor(sum, 1);
        sum += __shfl_xor(sum, 2);
        sum += __shfl_xor(sum, 4);
        sum += __shfl_xor(sum, 8);
        lst[i][r] = lst[i][r]*alpha + sum;
        mst[i][r] = nm;
        #pragma unroll
        for (int jd = 0; jd < 4; ++jd) oacc[i][jd][r] *= alpha;
      }
    }
    // P -> LDS (C layout to row-major [32][136])
    #pragma unroll
    for (int i = 0; i < 2; ++i)
      #pragma unroll
      for (int j = 0; j < 8; ++j)
        #pragma unroll
        for (int r = 0; r < 4; ++r)
          Ps[wave][(i*16 + quad*4 + r)*136 + j*16 + col] = f2b(sacc[i][j][r]);
    // O += P V  (contraction over s=128: 4 kfrags)
    #pragma unroll
    for (int i = 0; i < 2; ++i) {
      bf16x8 pa[4];
      #pragma unroll
      for (int kf = 0; kf < 4; ++kf)
        pa[kf] = *(const bf16x8*)&Ps[wave][(i*16 + col)*136 + kf*32 + quad*8];
      #pragma unroll
      for (int jd = 0; jd < 4; ++jd) {
        #pragma unroll
        for (int kf = 0; kf < 4; ++kf) {
          bf16x8 vbf = *(const bf16x8*)&Vs[(jd*16 + col)*136 + kf*32 + quad*8];
          oacc[i][jd] = __builtin_amdgcn_mfma_f32_16x16x32_bf16(pa[kf], vbf, oacc[i][jd], 0, 0, 0);
        }
      }
    }
  }
  // write O / l  -> ATTN[b,t, h*64+d] bf16
  #pragma unroll
  for (int i = 0; i < 2; ++i) {
    #pragma unroll
    for (int jd = 0; jd < 4; ++jd) {
      int d = jd*16 + col;
      #pragma unroll
      for (int r = 0; r < 4; ++r) {
        int t = t0 + wave*32 + i*16 + quad*4 + r;
        out[((size_t)(b*TT + t))*DM + h*64 + d] = f2b(oacc[i][jd][r] / lst[i][r]);
      }
    }
  }
}

// ---------------- token shift (bf16 in/out) ----------------------------------
__global__ void k_tshift(const bf16* __restrict__ H, const float* __restrict__ maak,
                         const float* __restrict__ maar,
                         bf16* __restrict__ XK, bf16* __restrict__ XR) {
  int idx = blockIdx.x*256 + threadIdx.x;   // B*T*DM total
  int c = idx & (DM - 1);
  int bt = idx >> 10;
  int t = bt & (TT - 1);
  float h = b2f(H[idx]);
  float prev = (t > 0) ? b2f(H[idx - DM]) : 0.f;
  float xx = prev - h;
  XK[idx] = f2b(h + xx*maak[c]);
  XR[idx] = f2b(h + xx*maar[c]);
}

// ---------------- final: out = x + sigmoid_r * kv ----------------------------
__global__ void k_final(const float* __restrict__ X, const float* __restrict__ R,
                        const float* __restrict__ KV, float* __restrict__ out) {
  int idx = blockIdx.x*256 + threadIdx.x;
  out[idx] = X[idx] + R[idx]*KV[idx];
}

// =============================================================================
extern "C" void kernel_launch(void* const* d_in, const int* in_sizes, int n_in,
                              void* d_out, int out_size, void* d_ws, size_t ws_size,
                              hipStream_t stream) {
  const float* x_in    = (const float*)d_in[0];
  const float* W_in    = (const float*)d_in[1];
  const float* conv_w  = (const float*)d_in[2];
  const float* conv_b  = (const float*)d_in[3];
  const float* A_log   = (const float*)d_in[4];
  const float* Dm      = (const float*)d_in[5];
  const float* dt_bias = (const float*)d_in[6];
  const float* mnorm_w = (const float*)d_in[7];
  const float* W_out   = (const float*)d_in[8];
  const float* W_qkv   = (const float*)d_in[9];
  const float* W_cproj = (const float*)d_in[10];
  const float* qconv_w = (const float*)d_in[11];
  const float* qconv_b = (const float*)d_in[12];
  const float* kconv_w = (const float*)d_in[13];
  const float* kconv_b = (const float*)d_in[14];
  const float* vconv_w = (const float*)d_in[15];
  const float* vconv_b = (const float*)d_in[16];
  const float* maa_k   = (const float*)d_in[17];
  const float* maa_r   = (const float*)d_in[18];
  const float* W_key   = (const float*)d_in[19];
  const float* W_rec   = (const float*)d_in[20];
  const float* W_val   = (const float*)d_in[21];
  float* out = (float*)d_out;

  float* ws = (float*)d_ws;
  // persistent regions (float-unit offsets), total 21,168,128 fl = 84.7 MB
  float* X       = ws;                       // [0, 2,097,152)
  bf16*  Hbf     = (bf16*)(ws + 2097152);    // 2,097,152 bf16
  float* Zbuf    = ws + 3145728;             // [.., +4,194,304)   z half of W_in out
  float* XBCDraw = ws + 7340032;             // [.., +4,784,128)   xBC+dt raw gemm out
  float* XBC     = ws + 12124160;            // [.., +4,718,592)   conv output
  float* DT      = ws + 16842752;            // [.., +65,536)
  float* CUM     = ws + 16908288;            // [.., +65,536)
  float* Y       = ws + 16973824;            // [.., +4,194,304)

  // lifetime-disjoint aliases
  bf16*  Wt_in    = (bf16*)XBC;              // step 2   (4480x1024 bf16)
  float* SC       = XBCDraw;                 // scan chunk states (4,194,304 fl)
  bf16*  Ybf      = (bf16*)XBC;              // steps 5-6 (2048x2048 bf16)
  bf16*  Wt_out   = (bf16*)(XBC + 2097152);  // step 6   (1024x2048 bf16)
  float* QKV      = Zbuf;                    // steps 8-9 (2048x1152)
  bf16*  Wt_qkv   = (bf16*)XBC;              // step 8   (1152x1024 bf16)
  bf16*  Qb       = (bf16*)XBCDraw;          // steps 9-10 (2048x1024 bf16)
  bf16*  Kb       = (bf16*)(XBCDraw + 1048576);   // 2048x64 bf16
  bf16*  Vtb      = (bf16*)(XBCDraw + 1114112);   // 2x64x1024 bf16 (d-major)
  bf16*  ATTNbf   = (bf16*)Y;                // steps 10-11 (2048x1024 bf16)
  bf16*  Wt_cproj = (bf16*)(Y + 1048576);    // step 11  (1024x1024 bf16)
  bf16*  XKbf     = (bf16*)XBC;              // steps 13-14 (2048x1024 bf16)
  bf16*  XRbf     = (bf16*)(XBC + 1048576);  // steps 13,16 (2048x1024 bf16)
  bf16*  Wt_key   = (bf16*)Zbuf;             // step 14  (4096x1024 bf16)
  bf16*  KFbf     = (bf16*)XBCDraw;          // steps 14-15 (2048x4096 bf16)
  bf16*  Wt_val   = (bf16*)Zbuf;             // step 15  (1024x4096 bf16)
  float* KV       = Y;                       // steps 15-17 (2048x1024)
  float* R        = Y + 2097152;             // steps 16-17 (2048x1024)
  bf16*  Wt_rec   = (bf16*)Zbuf;             // step 16  (1024x1024 bf16)

  dim3 thr256(256), thr512(512);
  dim3 tblk(32, 8);

  // 1. X = x; Hbf = rmsnorm(x)
  k_rms_in<<<BT, thr256, 0, stream>>>(x_in, X, Hbf);
  // 2. [Z | XBCDraw] = Hbf @ W_in  (split output; N padded to 4480 in Wt)
  k_tcast<<<dim3(4480/32, 1024/32), tblk, 0, stream>>>(W_in, Wt_in, 1024, NZX);
  mfma_gemm<0,false,false><<<dim3(2048/128, BT/128), thr256, 0, stream>>>(Hbf, Wt_in, Zbuf, nullptr, BT, 2048, 1024);
  mfma_gemm<0,false,false><<<dim3(19, BT/128), thr256, 0, stream>>>(Hbf, Wt_in + (size_t)2048*1024, XBCDraw, nullptr, BT, NXBCD, 1024);
  // 3. conv+silu on xBC, softplus dt
  k_conv_ssm<<<BT, thr256, 0, stream>>>(XBCDraw, conv_w, conv_b, dt_bias, XBC, DT);
  // 4. SSM chunked scan (SC aliases XBCDraw — dead after conv)
  k_scan1<<<BB*NHS*NC, thr512, 0, stream>>>(XBC, DT, A_log, Dm, Y, SC, CUM);
  k_scan2<<<BB*NHS, thr512, 0, stream>>>(SC, CUM);
  k_scan3<<<BB*NHS*NC, thr512, 0, stream>>>(XBC, SC, CUM, Y);
  // 5. gate + mnorm -> Ybf
  k_gate<<<BT, thr256, 0, stream>>>(Y, Zbuf, mnorm_w, Ybf);
  // 6. X += Ybf @ W_out  [2048,2048]x[2048,1024]
  k_tcast<<<dim3(1024/32, 2048/32), tblk, 0, stream>>>(W_out, Wt_out, 2048, 1024);
  mfma_gemm<0,true,false><<<dim3(1024/128, BT/128), thr256, 0, stream>>>(Ybf, Wt_out, X, nullptr, BT, 1024, 2048);
  // 7. Hbf = rmsnorm(X)
  k_rms_f32<<<BT, thr256, 0, stream>>>(X, Hbf);
  // 8. QKV = Hbf @ W_qkv  [2048,1024]x[1024,1152]
  k_tcast<<<dim3(1152/32, 1024/32), tblk, 0, stream>>>(W_qkv, Wt_qkv, 1024, 1152);
  mfma_gemm<0,false,false><<<dim3(1152/128, BT/128), thr256, 0, stream>>>(Hbf, Wt_qkv, QKV, nullptr, BT, 1152, 1024);
  // 9. q/k/v convs -> bf16 Qb (scaled), Kb, Vtb (transposed)
  k_conv_qkv<<<BT, thr256, 0, stream>>>(QKV, qconv_w, qconv_b, kconv_w, kconv_b, vconv_w, vconv_b, Qb, Kb, Vtb);
  // 10. MFMA flash attention -> ATTNbf
  k_flash<<<dim3(TT/128, NHA, BB), thr256, 0, stream>>>(Qb, Kb, Vtb, ATTNbf);
  // 11. X += ATTNbf @ W_cproj
  k_tcast<<<dim3(1024/32, 1024/32), tblk, 0, stream>>>(W_cproj, Wt_cproj, 1024, 1024);
  mfma_gemm<0,true,false><<<dim3(1024/128, BT/128), thr256, 0, stream>>>(ATTNbf, Wt_cproj, X, nullptr, BT, 1024, 1024);
  // 12. Hbf = rmsnorm(X)
  k_rms_f32<<<BT, thr256, 0, stream>>>(X, Hbf);
  // 13. token shift -> XKbf, XRbf
  k_tshift<<<(BT*DM)/256, thr256, 0, stream>>>(Hbf, maa_k, maa_r, XKbf, XRbf);
  // 14. KFbf = bf16(relu(XKbf @ W_key)^2)  [2048,1024]x[1024,4096]
  k_tcast<<<dim3(4096/32, 1024/32), tblk, 0, stream>>>(W_key, Wt_key, 1024, 4096);
  mfma_gemm<1,false,true><<<dim3(4096/128, BT/128), thr256, 0, stream>>>(XKbf, Wt_key, nullptr, KFbf, BT, 4096, 1024);
  // 15. KV = KFbf @ W_val  [2048,4096]x[4096,1024]
  k_tcast<<<dim3(1024/32, 4096/32), tblk, 0, stream>>>(W_val, Wt_val, 4096, 1024);
  mfma_gemm<0,false,false><<<dim3(1024/128, BT/128), thr256, 0, stream>>>(KFbf, Wt_val, KV, nullptr, BT, 1024, 4096);
  // 16. R = sigmoid(XRbf @ W_rec)
  k_tcast<<<dim3(1024/32, 1024/32), tblk, 0, stream>>>(W_rec, Wt_rec, 1024, 1024);
  mfma_gemm<2,false,false><<<dim3(1024/128, BT/128), thr256, 0, stream>>>(XRbf, Wt_rec, R, nullptr, BT, 1024, 1024);
  // 17. out = x + sigmoid_r * kv
  k_final<<<(BT*DM)/256, thr256, 0, stream>>>(X, R, KV, out);
}

// Round 6
// 691.795 us; speedup vs baseline: 6.3353x; 1.1836x over previous
//
#include <hip/hip_runtime.h>
#include <hip/hip_bf16.h>
#include <math.h>

#define BB 2
#define TT 1024
#define BT (BB*TT)          // 2048 rows
#define DM 1024
#define DI 2048
#define DS 128
#define NHS 32              // ssm heads
#define PDIM 64             // ssm headdim
#define NHA 16              // attn heads
#define HD 64
#define FFN_ 4096
#define NZX 4384            // 2*DI + 2*DS + NHS
#define NXBC 2304           // DI + 2*DS
#define NXBCD 2336          // xBC (2304) + dt (32) raw gemm-out width
#define CL 128              // scan chunk length
#define NC 8                // chunks

typedef __hip_bfloat16 bf16;
typedef short bf16x8 __attribute__((ext_vector_type(8)));
typedef float f32x4 __attribute__((ext_vector_type(4)));

__device__ __forceinline__ float b2f(bf16 v){ return __bfloat162float(v); }
__device__ __forceinline__ bf16 f2b(float v){ return __float2bfloat16(v); }

// ---------------- RMSNorm: write fp32 X copy + bf16 normalized H -------------
__global__ void k_rms_in(const float* __restrict__ xin, float* __restrict__ X,
                         bf16* __restrict__ H) {
  int row = blockIdx.x;
  int tid = threadIdx.x;          // 256 threads, 4 elems each (DM=1024)
  const float* xr = xin + (size_t)row * DM;
  float v[4]; float ss = 0.f;
  #pragma unroll
  for (int i = 0; i < 4; ++i) { v[i] = xr[tid*4+i]; ss += v[i]*v[i]; }
  __shared__ float red[256];
  red[tid] = ss; __syncthreads();
  for (int s = 128; s > 0; s >>= 1) { if (tid < s) red[tid] += red[tid+s]; __syncthreads(); }
  float scale = rsqrtf(red[0]/(float)DM + 1e-6f);
  float* Xr = X + (size_t)row*DM; bf16* Hr = H + (size_t)row*DM;
  #pragma unroll
  for (int i = 0; i < 4; ++i) { Xr[tid*4+i] = v[i]; Hr[tid*4+i] = f2b(v[i]*scale); }
}

__global__ void k_rms_f32(const float* __restrict__ X, bf16* __restrict__ H) {
  int row = blockIdx.x;
  int tid = threadIdx.x;
  const float* xr = X + (size_t)row * DM;
  float v[4]; float ss = 0.f;
  #pragma unroll
  for (int i = 0; i < 4; ++i) { v[i] = xr[tid*4+i]; ss += v[i]*v[i]; }
  __shared__ float red[256];
  red[tid] = ss; __syncthreads();
  for (int s = 128; s > 0; s >>= 1) { if (tid < s) red[tid] += red[tid+s]; __syncthreads(); }
  float scale = rsqrtf(red[0]/(float)DM + 1e-6f);
  bf16* Hr = H + (size_t)row*DM;
  #pragma unroll
  for (int i = 0; i < 4; ++i) Hr[tid*4+i] = f2b(v[i]*scale);
}

// ---------------- weight cast + transpose: Wt[n][k] = bf16(W[k][n]) ----------
__global__ void k_tcast(const float* __restrict__ W, bf16* __restrict__ Wt,
                        int K, int N) {
  __shared__ float t[32][33];
  int tx = threadIdx.x, ty = threadIdx.y;
  int n0 = blockIdx.x*32, k0 = blockIdx.y*32;
  #pragma unroll
  for (int i = 0; i < 4; ++i) {
    int k = k0 + ty + i*8, n = n0 + tx;
    t[ty + i*8][tx] = (n < N) ? W[(size_t)k*N + n] : 0.f;
  }
  __syncthreads();
  #pragma unroll
  for (int i = 0; i < 4; ++i) {
    int n = n0 + ty + i*8, k = k0 + tx;
    Wt[(size_t)n*K + k] = f2b(t[tx][ty + i*8]);
  }
}

// ---------------- MFMA GEMM: C[M,N] = epi(A[M,K] @ Bt[N,K]^T) ----------------
template<int EPI, bool ADD, bool OUTBF>
__global__ __launch_bounds__(256)
void mfma_gemm(const bf16* __restrict__ A, const bf16* __restrict__ Bt,
               float* __restrict__ C, bf16* __restrict__ Cbf,
               int M, int N, int K) {
  __shared__ bf16 As[128*32];
  __shared__ bf16 Bs[128*32];
  int tid = threadIdx.x;
  int wave = tid >> 6, lane = tid & 63;
  int m_l = lane & 15, quad = lane >> 4;
  int wr = (wave & 1) * 64, wc = (wave >> 1) * 64;
  int row0 = blockIdx.y * 128, col0 = blockIdx.x * 128;
  f32x4 acc[4][4];
  #pragma unroll
  for (int i = 0; i < 4; ++i)
    #pragma unroll
    for (int j = 0; j < 4; ++j) acc[i][j] = (f32x4){0.f,0.f,0.f,0.f};
  int r_a = tid >> 2;            // 0..63
  int kc  = (tid & 3) * 8;       // 0,8,16,24
  for (int k0 = 0; k0 < K; k0 += 32) {
    uint4 av0 = *(const uint4*)&A [(size_t)(row0      + r_a) * K + k0 + kc];
    uint4 av1 = *(const uint4*)&A [(size_t)(row0 + 64 + r_a) * K + k0 + kc];
    uint4 bv0 = *(const uint4*)&Bt[(size_t)(col0      + r_a) * K + k0 + kc];
    uint4 bv1 = *(const uint4*)&Bt[(size_t)(col0 + 64 + r_a) * K + k0 + kc];
    __syncthreads();
    *(uint4*)&As[(     r_a) * 32 + kc] = av0;
    *(uint4*)&As[(64 + r_a) * 32 + kc] = av1;
    *(uint4*)&Bs[(     r_a) * 32 + kc] = bv0;
    *(uint4*)&Bs[(64 + r_a) * 32 + kc] = bv1;
    __syncthreads();
    bf16x8 af[4], bfv[4];
    #pragma unroll
    for (int i = 0; i < 4; ++i) af[i]  = *(const bf16x8*)&As[(wr + i*16 + m_l)*32 + quad*8];
    #pragma unroll
    for (int j = 0; j < 4; ++j) bfv[j] = *(const bf16x8*)&Bs[(wc + j*16 + m_l)*32 + quad*8];
    #pragma unroll
    for (int i = 0; i < 4; ++i)
      #pragma unroll
      for (int j = 0; j < 4; ++j)
        acc[i][j] = __builtin_amdgcn_mfma_f32_16x16x32_bf16(af[i], bfv[j], acc[i][j], 0, 0, 0);
  }
  #pragma unroll
  for (int i = 0; i < 4; ++i) {
    #pragma unroll
    for (int j = 0; j < 4; ++j) {
      int col = col0 + wc + j*16 + m_l;
      if (col < N) {
        #pragma unroll
        for (int r = 0; r < 4; ++r) {
          int row = row0 + wr + i*16 + quad*4 + r;
          float v = acc[i][j][r];
          if (EPI == 1) { v = fmaxf(v, 0.f); v = v*v; }          // relu^2
          else if (EPI == 2) v = 1.f/(1.f + __expf(-v));          // sigmoid
          if (OUTBF)      Cbf[(size_t)row*N + col] = f2b(v);
          else if (ADD)   C[(size_t)row*N + col] += v;
          else            C[(size_t)row*N + col]  = v;
        }
      }
    }
  }
}

// ---------------- SSM conv (K=4) + silu + dt softplus; bf16 xBC out ----------
__global__ void k_conv_ssm(const float* __restrict__ ZXr, const float* __restrict__ cw,
                           const float* __restrict__ cb, const float* __restrict__ dtb,
                           bf16* __restrict__ XBCb, float* __restrict__ DT) {
  int bt = blockIdx.x; int b = bt >> 10; int t = bt & 1023;
  int tid = threadIdx.x;
  for (int c = tid; c < NXBC; c += 256) {
    float acc = cb[c];
    #pragma unroll
    for (int kk = 0; kk < 4; ++kk) {
      int ts = t - 3 + kk;
      if (ts >= 0) acc += cw[c*4+kk] * ZXr[((size_t)(b*TT+ts))*NXBCD + c];
    }
    float s = acc / (1.f + __expf(-acc));  // silu
    XBCb[(size_t)bt*NXBC + c] = f2b(s);
  }
  if (tid < NHS) {
    float x = ZXr[(size_t)bt*NXBCD + NXBC + tid] + dtb[tid];
    float sp = (x > 20.f) ? x : log1pf(__expf(x));
    DT[(size_t)bt*NHS + tid] = sp;
  }
}

// ---------------- scan pass 1: intra-chunk via MFMA (Mamba2 chunked) ---------
// grid 512 = bh*8 + c; 256 thr = 4 waves. Per block:
//  G = C @ B^T; P = G*exp(L_t-L_s)*dt_s (s<=t); Y = P@X + x*D;
//  SC[p][n] = X^T @ (w_s B); CUM[t] = exp(L_t).
__global__ __launch_bounds__(256)
void k_scan1(const bf16* __restrict__ xbcb, const float* __restrict__ dt,
             const float* __restrict__ A_log, const float* __restrict__ Dmv,
             float* __restrict__ Y, float* __restrict__ SC, float* __restrict__ CUM) {
  int bc = blockIdx.x;
  int bh = bc >> 3, c = bc & 7;
  int b = bh >> 5, h = bh & 31;
  int tid = threadIdx.x, wave = tid >> 6, lane = tid & 63;
  int col = lane & 15, quad = lane >> 4;
  int t0 = c * CL;
  __shared__ bf16 sB[128*136];   // B rows [s][n]; later BwT [n][s]
  __shared__ bf16 sC[128*136];   // C rows [t][n]; later Ps [t][s]
  __shared__ bf16 sxT[64*136];   // x^T [p][t]
  __shared__ float sL[128], sdt[128];
  float A = -__expf(A_log[h]);
  float Dmh = Dmv[h];
  // stage B, C tiles (vector), xT (transposed scalar), dt
  for (int e = tid; e < 128*16; e += 256) {
    int r = e >> 4, ch = e & 15;
    const bf16* row = xbcb + (size_t)(b*TT + t0 + r)*NXBC;
    *(uint4*)&sB[r*136 + ch*8] = *(const uint4*)&row[2048 + ch*8];
    *(uint4*)&sC[r*136 + ch*8] = *(const uint4*)&row[2176 + ch*8];
  }
  for (int e = tid; e < 64*128; e += 256) {
    int p = e & 63, t = e >> 6;
    sxT[p*136 + t] = xbcb[(size_t)(b*TT + t0 + t)*NXBC + h*64 + p];
  }
  if (tid < 128) sdt[tid] = dt[(size_t)(b*TT + t0 + tid)*NHS + h];
  __syncthreads();
  // inclusive log-decay prefix: L_t = sum_{u<=t} dt_u*A  (wave 0)
  if (wave == 0) {
    float a0 = sdt[2*lane]*A, a1 = sdt[2*lane+1]*A;
    float tot = a0 + a1;
    #pragma unroll
    for (int off = 1; off < 64; off <<= 1) {
      float up = __shfl_up(tot, off);
      if (lane >= off) tot += up;
    }
    sL[2*lane+1] = tot;
    sL[2*lane]   = tot - a1;
  }
  __syncthreads();
  // G = C @ B^T : 128x128, wave quadrant 64x64
  int wr = (wave & 1)*64, wc = (wave >> 1)*64;
  f32x4 g[4][4];
  #pragma unroll
  for (int i = 0; i < 4; ++i)
    #pragma unroll
    for (int j = 0; j < 4; ++j) g[i][j] = (f32x4){0.f,0.f,0.f,0.f};
  #pragma unroll
  for (int kf = 0; kf < 4; ++kf) {
    bf16x8 af[4], bfr[4];
    #pragma unroll
    for (int i = 0; i < 4; ++i) af[i]  = *(const bf16x8*)&sC[(wr + i*16 + col)*136 + kf*32 + quad*8];
    #pragma unroll
    for (int j = 0; j < 4; ++j) bfr[j] = *(const bf16x8*)&sB[(wc + j*16 + col)*136 + kf*32 + quad*8];
    #pragma unroll
    for (int i = 0; i < 4; ++i)
      #pragma unroll
      for (int j = 0; j < 4; ++j)
        g[i][j] = __builtin_amdgcn_mfma_f32_16x16x32_bf16(af[i], bfr[j], g[i][j], 0, 0, 0);
  }
  __syncthreads();   // all waves done reading sB/sC
  // CUM
  if (tid < 128) CUM[(size_t)bh*TT + t0 + tid] = __expf(sL[tid]);
  float Lend = sL[127];
  // P into sC (C-layout -> row-major [t][s])
  #pragma unroll
  for (int i = 0; i < 4; ++i) {
    #pragma unroll
    for (int j = 0; j < 4; ++j) {
      int sl = wc + j*16 + col;
      #pragma unroll
      for (int r = 0; r < 4; ++r) {
        int tl = wr + i*16 + quad*4 + r;
        float v = (sl <= tl) ? g[i][j][r] * __expf(sL[tl] - sL[sl]) * sdt[sl] : 0.f;
        sC[tl*136 + sl] = f2b(v);
      }
    }
  }
  // BwT[n][s] = B[s][n]*w_s into sB  (w_s = exp(Lend-L_s)*dt_s)
  for (int e = tid; e < 128*128; e += 256) {
    int n = e & 127, s = e >> 7;
    float w = __expf(Lend - sL[s]) * sdt[s];
    sB[n*136 + s] = f2b(b2f(xbcb[(size_t)(b*TT + t0 + s)*NXBC + 2048 + n]) * w);
  }
  __syncthreads();
  // Y = P @ X : each wave 32 t-rows x 64 p
  f32x4 ya[2][4];
  #pragma unroll
  for (int i2 = 0; i2 < 2; ++i2)
    #pragma unroll
    for (int jd = 0; jd < 4; ++jd) ya[i2][jd] = (f32x4){0.f,0.f,0.f,0.f};
  #pragma unroll
  for (int kf = 0; kf < 4; ++kf) {
    bf16x8 pa[2], xa[4];
    #pragma unroll
    for (int i2 = 0; i2 < 2; ++i2)
      pa[i2] = *(const bf16x8*)&sC[(wave*32 + i2*16 + col)*136 + kf*32 + quad*8];
    #pragma unroll
    for (int jd = 0; jd < 4; ++jd)
      xa[jd] = *(const bf16x8*)&sxT[(jd*16 + col)*136 + kf*32 + quad*8];
    #pragma unroll
    for (int i2 = 0; i2 < 2; ++i2)
      #pragma unroll
      for (int jd = 0; jd < 4; ++jd)
        ya[i2][jd] = __builtin_amdgcn_mfma_f32_16x16x32_bf16(pa[i2], xa[jd], ya[i2][jd], 0, 0, 0);
  }
  #pragma unroll
  for (int i2 = 0; i2 < 2; ++i2) {
    #pragma unroll
    for (int jd = 0; jd < 4; ++jd) {
      int p = jd*16 + col;
      #pragma unroll
      for (int r = 0; r < 4; ++r) {
        int tl = wave*32 + i2*16 + quad*4 + r;
        float xv = b2f(sxT[p*136 + tl]);
        Y[(size_t)(b*TT + t0 + tl)*DI + h*64 + p] = ya[i2][jd][r] + xv*Dmh;
      }
    }
  }
  // SC[p][n] = X^T @ BwT^T : wave handles 16 p-rows, 8 n-tiles
  f32x4 sa[8];
  #pragma unroll
  for (int nt = 0; nt < 8; ++nt) sa[nt] = (f32x4){0.f,0.f,0.f,0.f};
  #pragma unroll
  for (int kf = 0; kf < 4; ++kf) {
    bf16x8 xpa = *(const bf16x8*)&sxT[(wave*16 + col)*136 + kf*32 + quad*8];
    #pragma unroll
    for (int nt = 0; nt < 8; ++nt) {
      bf16x8 bwa = *(const bf16x8*)&sB[(nt*16 + col)*136 + kf*32 + quad*8];
      sa[nt] = __builtin_amdgcn_mfma_f32_16x16x32_bf16(xpa, bwa, sa[nt], 0, 0, 0);
    }
  }
  #pragma unroll
  for (int nt = 0; nt < 8; ++nt) {
    int n = nt*16 + col;
    #pragma unroll
    for (int r = 0; r < 4; ++r) {
      int p = wave*16 + quad*4 + r;
      SC[((size_t)(bh*NC + c)*64 + p)*128 + n] = sa[nt][r];
    }
  }
}

// ---------------- scan pass 2: sequential inter-chunk combine (fp32) ---------
__global__ __launch_bounds__(512)
void k_scan2(float* __restrict__ SC, const float* __restrict__ CUM) {
  int bh = blockIdx.x;
  int tid = threadIdx.x;
  int p = tid >> 3, g = tid & 7;
  float S[16];
  #pragma unroll
  for (int j = 0; j < 16; ++j) S[j] = 0.f;
  for (int c = 0; c < NC; ++c) {
    size_t base = ((size_t)(bh*NC + c)*64 + p)*128 + g*16;
    float Ptot = CUM[(size_t)bh*TT + c*CL + (CL-1)];
    float tmp[16];
    #pragma unroll
    for (int j = 0; j < 16; ++j) tmp[j] = SC[base + j];
    #pragma unroll
    for (int j = 0; j < 16; ++j) SC[base + j] = S[j];
    #pragma unroll
    for (int j = 0; j < 16; ++j) S[j] = S[j]*Ptot + tmp[j];
  }
}

// ---------------- scan pass 3: Y += CUM[t] * (C @ S_init^T) via MFMA ---------
__global__ __launch_bounds__(256)
void k_scan3(const bf16* __restrict__ xbcb, const float* __restrict__ SC,
             const float* __restrict__ CUM, float* __restrict__ Y) {
  int bc = blockIdx.x;
  int bh = bc >> 3, c = bc & 7;
  if (c == 0) return;
  int b = bh >> 5, h = bh & 31;
  int tid = threadIdx.x, wave = tid >> 6, lane = tid & 63;
  int col = lane & 15, quad = lane >> 4;
  int t0 = c * CL;
  __shared__ bf16 sCt[128*136];  // C rows [t][n]
  __shared__ bf16 sS[64*136];    // S [p][n]
  __shared__ float sCum[128];
  for (int e = tid; e < 128*16; e += 256) {
    int r = e >> 4, ch = e & 15;
    *(uint4*)&sCt[r*136 + ch*8] =
      *(const uint4*)&xbcb[(size_t)(b*TT + t0 + r)*NXBC + 2176 + ch*8];
  }
  for (int e = tid; e < 64*128; e += 256) {
    int n = e & 127, p = e >> 7;
    sS[p*136 + n] = f2b(SC[((size_t)(bh*NC + c)*64 + p)*128 + n]);
  }
  if (tid < 128) sCum[tid] = CUM[(size_t)bh*TT + t0 + tid];
  __syncthreads();
  f32x4 ya[2][4];
  #pragma unroll
  for (int i2 = 0; i2 < 2; ++i2)
    #pragma unroll
    for (int jd = 0; jd < 4; ++jd) ya[i2][jd] = (f32x4){0.f,0.f,0.f,0.f};
  #pragma unroll
  for (int kf = 0; kf < 4; ++kf) {
    bf16x8 pa[2], sv[4];
    #pragma unroll
    for (int i2 = 0; i2 < 2; ++i2)
      pa[i2] = *(const bf16x8*)&sCt[(wave*32 + i2*16 + col)*136 + kf*32 + quad*8];
    #pragma unroll
    for (int jd = 0; jd < 4; ++jd)
      sv[jd] = *(const bf16x8*)&sS[(jd*16 + col)*136 + kf*32 + quad*8];
    #pragma unroll
    for (int i2 = 0; i2 < 2; ++i2)
      #pragma unroll
      for (int jd = 0; jd < 4; ++jd)
        ya[i2][jd] = __builtin_amdgcn_mfma_f32_16x16x32_bf16(pa[i2], sv[jd], ya[i2][jd], 0, 0, 0);
  }
  #pragma unroll
  for (int i2 = 0; i2 < 2; ++i2) {
    #pragma unroll
    for (int jd = 0; jd < 4; ++jd) {
      int p = jd*16 + col;
      #pragma unroll
      for (int r = 0; r < 4; ++r) {
        int tl = wave*32 + i2*16 + quad*4 + r;
        Y[(size_t)(b*TT + t0 + tl)*DI + h*64 + p] += sCum[tl]*ya[i2][jd][r];
      }
    }
  }
}

// ---------------- gate: Ybf = bf16(rmsnorm(y * silu(z)) * mnorm_w) -----------
__global__ void k_gate(const float* __restrict__ Y, const float* __restrict__ Z,
                       const float* __restrict__ mnw, bf16* __restrict__ Ybf) {
  int row = blockIdx.x; int tid = threadIdx.x;  // 256 thr, 8 elems each (DI=2048)
  const float* yr = Y + (size_t)row*DI;
  const float* zr = Z + (size_t)row*DI;
  float gv[8]; float ss = 0.f;
  #pragma unroll
  for (int i = 0; i < 8; ++i) {
    int c = tid*8 + i;
    float z = zr[c];
    float sz = z / (1.f + __expf(-z));
    float v = yr[c]*sz;
    gv[i] = v; ss += v*v;
  }
  __shared__ float red[256];
  red[tid] = ss; __syncthreads();
  for (int s = 128; s > 0; s >>= 1) { if (tid < s) red[tid] += red[tid+s]; __syncthreads(); }
  float scale = rsqrtf(red[0]/(float)DI + 1e-5f);
  bf16* br = Ybf + (size_t)row*DI;
  #pragma unroll
  for (int i = 0; i < 8; ++i) { int c = tid*8 + i; br[c] = f2b(gv[i]*scale*mnw[c]); }
}

// ---------------- q/k/v causal dwconv (K=3), bf16 out, Q pre-scaled, V^T -----
__global__ void k_conv_qkv(const float* __restrict__ QKV,
                           const float* qw, const float* qb, const float* kw, const float* kb,
                           const float* vw, const float* vb,
                           bf16* __restrict__ Qb, bf16* __restrict__ Kb, bf16* __restrict__ Vtb) {
  int bt = blockIdx.x; int b = bt >> 10; int t = bt & 1023;
  int tid = threadIdx.x;
  for (int c = tid; c < 1152; c += 256) {
    if (c < 1024) {
      int h = c >> 6, d = c & 63;
      float acc = qb[d];
      #pragma unroll
      for (int kk = 0; kk < 3; ++kk) { int ts = t-2+kk; if (ts >= 0) acc += qw[d*3+kk] * QKV[((size_t)(b*TT+ts))*1152 + c]; }
      Qb[((size_t)(b*NHA + h)*TT + t)*HD + d] = f2b(acc * 0.125f);  // 1/sqrt(64)
    } else if (c < 1088) {
      int d = c - 1024;
      float acc = kb[d];
      #pragma unroll
      for (int kk = 0; kk < 3; ++kk) { int ts = t-2+kk; if (ts >= 0) acc += kw[d*3+kk] * QKV[((size_t)(b*TT+ts))*1152 + c]; }
      Kb[(size_t)bt*HD + d] = f2b(acc);
    } else {
      int d = c - 1088;
      float acc = vb[d];
      #pragma unroll
      for (int kk = 0; kk < 3; ++kk) { int ts = t-2+kk; if (ts >= 0) acc += vw[d*3+kk] * QKV[((size_t)(b*TT+ts))*1152 + c]; }
      Vtb[((size_t)(b*HD + d))*TT + t] = f2b(acc);
    }
  }
}

// ---------------- MFMA flash attention ---------------------------------------
__global__ __launch_bounds__(256)
void k_flash(const bf16* __restrict__ Qb, const bf16* __restrict__ Kb,
             const bf16* __restrict__ Vtb, bf16* __restrict__ out) {
  int qt = blockIdx.x, h = blockIdx.y, b = blockIdx.z;
  int tid = threadIdx.x, wave = tid >> 6, lane = tid & 63;
  int col = lane & 15, quad = lane >> 4;
  int t0 = qt * 128;
  __shared__ bf16 Ks[128*72];     // K rows, padded 64->72
  __shared__ bf16 Vs[64*136];     // V^T rows (d-major), padded 128->136
  __shared__ bf16 Ps[4][32*136];  // per-wave P (A-layout staging)
  const bf16* Qbase = Qb + ((size_t)(b*NHA + h))*TT*HD;
  bf16x8 qf[2][2];
  #pragma unroll
  for (int i = 0; i < 2; ++i)
    #pragma unroll
    for (int kf = 0; kf < 2; ++kf)
      qf[i][kf] = *(const bf16x8*)&Qbase[(size_t)(t0 + wave*32 + i*16 + col)*HD + kf*32 + quad*8];
  float mst[2][4], lst[2][4];
  f32x4 oacc[2][4];
  #pragma unroll
  for (int i = 0; i < 2; ++i)
    #pragma unroll
    for (int r = 0; r < 4; ++r) { mst[i][r] = -1e30f; lst[i][r] = 0.f; }
  #pragma unroll
  for (int i = 0; i < 2; ++i)
    #pragma unroll
    for (int jd = 0; jd < 4; ++jd) oacc[i][jd] = (f32x4){0.f,0.f,0.f,0.f};

  for (int kt = 0; kt <= qt; ++kt) {
    int s0 = kt * 128;
    __syncthreads();
    for (int e = tid; e < 1024; e += 256) {
      int r = e >> 3, ch = e & 7;
      *(uint4*)&Ks[r*72 + ch*8] = *(const uint4*)&Kb[((size_t)(b*TT + s0 + r))*HD + ch*8];
    }
    for (int e = tid; e < 1024; e += 256) {
      int d = e >> 4, ch = e & 15;
      *(uint4*)&Vs[d*136 + ch*8] = *(const uint4*)&Vtb[((size_t)(b*HD + d))*TT + s0 + ch*8];
    }
    __syncthreads();
    f32x4 sacc[2][8];
    #pragma unroll
    for (int i = 0; i < 2; ++i)
      #pragma unroll
      for (int j = 0; j < 8; ++j) sacc[i][j] = (f32x4){0.f,0.f,0.f,0.f};
    #pragma unroll
    for (int j = 0; j < 8; ++j) {
      bf16x8 kf0 = *(const bf16x8*)&Ks[(j*16 + col)*72 + quad*8];
      bf16x8 kf1 = *(const bf16x8*)&Ks[(j*16 + col)*72 + 32 + quad*8];
      #pragma unroll
      for (int i = 0; i < 2; ++i) {
        sacc[i][j] = __builtin_amdgcn_mfma_f32_16x16x32_bf16(qf[i][0], kf0, sacc[i][j], 0, 0, 0);
        sacc[i][j] = __builtin_amdgcn_mfma_f32_16x16x32_bf16(qf[i][1], kf1, sacc[i][j], 0, 0, 0);
      }
    }
    bool diag = (kt == qt);
    #pragma unroll
    for (int i = 0; i < 2; ++i) {
      #pragma unroll
      for (int r = 0; r < 4; ++r) {
        int rowloc = wave*32 + i*16 + quad*4 + r;
        if (diag) {
          #pragma unroll
          for (int j = 0; j < 8; ++j)
            if (j*16 + col > rowloc) sacc[i][j][r] = -1e30f;
        }
        float mx = -1e30f;
        #pragma unroll
        for (int j = 0; j < 8; ++j) mx = fmaxf(mx, sacc[i][j][r]);
        mx = fmaxf(mx, __shfl_xor(mx, 1));
        mx = fmaxf(mx, __shfl_xor(mx, 2));
        mx = fmaxf(mx, __shfl_xor(mx, 4));
        mx = fmaxf(mx, __shfl_xor(mx, 8));
        float nm = fmaxf(mst[i][r], mx);
        float alpha = __expf(mst[i][r] - nm);
        float sum = 0.f;
        #pragma unroll
        for (int j = 0; j < 8; ++j) {
          float pv = __expf(sacc[i][j][r] - nm);
          sacc[i][j][r] = pv; sum += pv;
        }
        sum += __shfl_xor(sum, 1);
        sum += __shfl_xor(sum, 2);
        sum += __shfl_xor(sum, 4);
        sum += __shfl_xor(sum, 8);
        lst[i][r] = lst[i][r]*alpha + sum;
        mst[i][r] = nm;
        #pragma unroll
        for (int jd = 0; jd < 4; ++jd) oacc[i][jd][r] *= alpha;
      }
    }
    #pragma unroll
    for (int i = 0; i < 2; ++i)
      #pragma unroll
      for (int j = 0; j < 8; ++j)
        #pragma unroll
        for (int r = 0; r < 4; ++r)
          Ps[wave][(i*16 + quad*4 + r)*136 + j*16 + col] = f2b(sacc[i][j][r]);
    #pragma unroll
    for (int i = 0; i < 2; ++i) {
      bf16x8 pa[4];
      #pragma unroll
      for (int kf = 0; kf < 4; ++kf)
        pa[kf] = *(const bf16x8*)&Ps[wave][(i*16 + col)*136 + kf*32 + quad*8];
      #pragma unroll
      for (int jd = 0; jd < 4; ++jd) {
        #pragma unroll
        for (int kf = 0; kf < 4; ++kf) {
          bf16x8 vbf = *(const bf16x8*)&Vs[(jd*16 + col)*136 + kf*32 + quad*8];
          oacc[i][jd] = __builtin_amdgcn_mfma_f32_16x16x32_bf16(pa[kf], vbf, oacc[i][jd], 0, 0, 0);
        }
      }
    }
  }
  #pragma unroll
  for (int i = 0; i < 2; ++i) {
    #pragma unroll
    for (int jd = 0; jd < 4; ++jd) {
      int d = jd*16 + col;
      #pragma unroll
      for (int r = 0; r < 4; ++r) {
        int t = t0 + wave*32 + i*16 + quad*4 + r;
        out[((size_t)(b*TT + t))*DM + h*64 + d] = f2b(oacc[i][jd][r] / lst[i][r]);
      }
    }
  }
}

// ---------------- token shift (bf16 in/out) ----------------------------------
__global__ void k_tshift(const bf16* __restrict__ H, const float* __restrict__ maak,
                         const float* __restrict__ maar,
                         bf16* __restrict__ XK, bf16* __restrict__ XR) {
  int idx = blockIdx.x*256 + threadIdx.x;   // B*T*DM total
  int c = idx & (DM - 1);
  int bt = idx >> 10;
  int t = bt & (TT - 1);
  float h = b2f(H[idx]);
  float prev = (t > 0) ? b2f(H[idx - DM]) : 0.f;
  float xx = prev - h;
  XK[idx] = f2b(h + xx*maak[c]);
  XR[idx] = f2b(h + xx*maar[c]);
}

// ---------------- final: out = x + sigmoid_r * kv ----------------------------
__global__ void k_final(const float* __restrict__ X, const float* __restrict__ R,
                        const float* __restrict__ KV, float* __restrict__ out) {
  int idx = blockIdx.x*256 + threadIdx.x;
  out[idx] = X[idx] + R[idx]*KV[idx];
}

// =============================================================================
extern "C" void kernel_launch(void* const* d_in, const int* in_sizes, int n_in,
                              void* d_out, int out_size, void* d_ws, size_t ws_size,
                              hipStream_t stream) {
  const float* x_in    = (const float*)d_in[0];
  const float* W_in    = (const float*)d_in[1];
  const float* conv_w  = (const float*)d_in[2];
  const float* conv_b  = (const float*)d_in[3];
  const float* A_log   = (const float*)d_in[4];
  const float* Dm      = (const float*)d_in[5];
  const float* dt_bias = (const float*)d_in[6];
  const float* mnorm_w = (const float*)d_in[7];
  const float* W_out   = (const float*)d_in[8];
  const float* W_qkv   = (const float*)d_in[9];
  const float* W_cproj = (const float*)d_in[10];
  const float* qconv_w = (const float*)d_in[11];
  const float* qconv_b = (const float*)d_in[12];
  const float* kconv_w = (const float*)d_in[13];
  const float* kconv_b = (const float*)d_in[14];
  const float* vconv_w = (const float*)d_in[15];
  const float* vconv_b = (const float*)d_in[16];
  const float* maa_k   = (const float*)d_in[17];
  const float* maa_r   = (const float*)d_in[18];
  const float* W_key   = (const float*)d_in[19];
  const float* W_rec   = (const float*)d_in[20];
  const float* W_val   = (const float*)d_in[21];
  float* out = (float*)d_out;

  float* ws = (float*)d_ws;
  // persistent regions (float-unit offsets), total 21,168,128 fl = 84.7 MB
  float* X       = ws;                       // [0, 2,097,152)
  bf16*  Hbf     = (bf16*)(ws + 2097152);    // 2,097,152 bf16
  float* Zbuf    = ws + 3145728;             // [.., +4,194,304)   z half of W_in out
  float* XBCDraw = ws + 7340032;             // [.., +4,784,128)   xBC+dt raw gemm out
  float* XBC     = ws + 12124160;            // [.., +4,718,592)   conv output (bf16 now)
  float* DT      = ws + 16842752;            // [.., +65,536)
  float* CUM     = ws + 16908288;            // [.., +65,536)
  float* Y       = ws + 16973824;            // [.., +4,194,304)

  // lifetime-disjoint aliases
  bf16*  Wt_in    = (bf16*)XBC;              // step 2   (4480x1024 bf16)
  bf16*  XBCb     = (bf16*)XBC;              // steps 3-4 (2048x2304 bf16)
  float* SC       = XBCDraw;                 // scan chunk states (4,194,304 fl)
  bf16*  Ybf      = (bf16*)XBC;              // steps 5-6 (2048x2048 bf16)
  bf16*  Wt_out   = (bf16*)(XBC + 2097152);  // step 6   (1024x2048 bf16)
  float* QKV      = Zbuf;                    // steps 8-9 (2048x1152)
  bf16*  Wt_qkv   = (bf16*)XBC;              // step 8   (1152x1024 bf16)
  bf16*  Qb       = (bf16*)XBCDraw;          // steps 9-10 (2048x1024 bf16)
  bf16*  Kb       = (bf16*)(XBCDraw + 1048576);   // 2048x64 bf16
  bf16*  Vtb      = (bf16*)(XBCDraw + 1114112);   // 2x64x1024 bf16 (d-major)
  bf16*  ATTNbf   = (bf16*)Y;                // steps 10-11 (2048x1024 bf16)
  bf16*  Wt_cproj = (bf16*)(Y + 1048576);    // step 11  (1024x1024 bf16)
  bf16*  XKbf     = (bf16*)XBC;              // steps 13-14 (2048x1024 bf16)
  bf16*  XRbf     = (bf16*)(XBC + 1048576);  // steps 13,16 (2048x1024 bf16)
  bf16*  Wt_key   = (bf16*)Zbuf;             // step 14  (4096x1024 bf16)
  bf16*  KFbf     = (bf16*)XBCDraw;          // steps 14-15 (2048x4096 bf16)
  bf16*  Wt_val   = (bf16*)Zbuf;             // step 15  (1024x4096 bf16)
  float* KV       = Y;                       // steps 15-17 (2048x1024)
  float* R        = Y + 2097152;             // steps 16-17 (2048x1024)
  bf16*  Wt_rec   = (bf16*)Zbuf;             // step 16  (1024x1024 bf16)

  dim3 thr256(256), thr512(512);
  dim3 tblk(32, 8);

  // 1. X = x; Hbf = rmsnorm(x)
  k_rms_in<<<BT, thr256, 0, stream>>>(x_in, X, Hbf);
  // 2. [Z | XBCDraw] = Hbf @ W_in  (split output; N padded to 4480 in Wt)
  k_tcast<<<dim3(4480/32, 1024/32), tblk, 0, stream>>>(W_in, Wt_in, 1024, NZX);
  mfma_gemm<0,false,false><<<dim3(2048/128, BT/128), thr256, 0, stream>>>(Hbf, Wt_in, Zbuf, nullptr, BT, 2048, 1024);
  mfma_gemm<0,false,false><<<dim3(19, BT/128), thr256, 0, stream>>>(Hbf, Wt_in + (size_t)2048*1024, XBCDraw, nullptr, BT, NXBCD, 1024);
  // 3. conv+silu on xBC (bf16 out), softplus dt
  k_conv_ssm<<<BT, thr256, 0, stream>>>(XBCDraw, conv_w, conv_b, dt_bias, XBCb, DT);
  // 4. SSM chunked scan via MFMA (SC aliases XBCDraw — dead after conv)
  k_scan1<<<BB*NHS*NC, thr256, 0, stream>>>(XBCb, DT, A_log, Dm, Y, SC, CUM);
  k_scan2<<<BB*NHS, thr512, 0, stream>>>(SC, CUM);
  k_scan3<<<BB*NHS*NC, thr256, 0, stream>>>(XBCb, SC, CUM, Y);
  // 5. gate + mnorm -> Ybf
  k_gate<<<BT, thr256, 0, stream>>>(Y, Zbuf, mnorm_w, Ybf);
  // 6. X += Ybf @ W_out  [2048,2048]x[2048,1024]
  k_tcast<<<dim3(1024/32, 2048/32), tblk, 0, stream>>>(W_out, Wt_out, 2048, 1024);
  mfma_gemm<0,true,false><<<dim3(1024/128, BT/128), thr256, 0, stream>>>(Ybf, Wt_out, X, nullptr, BT, 1024, 2048);
  // 7. Hbf = rmsnorm(X)
  k_rms_f32<<<BT, thr256, 0, stream>>>(X, Hbf);
  // 8. QKV = Hbf @ W_qkv  [2048,1024]x[1024,1152]
  k_tcast<<<dim3(1152/32, 1024/32), tblk, 0, stream>>>(W_qkv, Wt_qkv, 1024, 1152);
  mfma_gemm<0,false,false><<<dim3(1152/128, BT/128), thr256, 0, stream>>>(Hbf, Wt_qkv, QKV, nullptr, BT, 1152, 1024);
  // 9. q/k/v convs -> bf16 Qb (scaled), Kb, Vtb (transposed)
  k_conv_qkv<<<BT, thr256, 0, stream>>>(QKV, qconv_w, qconv_b, kconv_w, kconv_b, vconv_w, vconv_b, Qb, Kb, Vtb);
  // 10. MFMA flash attention -> ATTNbf
  k_flash<<<dim3(TT/128, NHA, BB), thr256, 0, stream>>>(Qb, Kb, Vtb, ATTNbf);
  // 11. X += ATTNbf @ W_cproj
  k_tcast<<<dim3(1024/32, 1024/32), tblk, 0, stream>>>(W_cproj, Wt_cproj, 1024, 1024);
  mfma_gemm<0,true,false><<<dim3(1024/128, BT/128), thr256, 0, stream>>>(ATTNbf, Wt_cproj, X, nullptr, BT, 1024, 1024);
  // 12. Hbf = rmsnorm(X)
  k_rms_f32<<<BT, thr256, 0, stream>>>(X, Hbf);
  // 13. token shift -> XKbf, XRbf
  k_tshift<<<(BT*DM)/256, thr256, 0, stream>>>(Hbf, maa_k, maa_r, XKbf, XRbf);
  // 14. KFbf = bf16(relu(XKbf @ W_key)^2)  [2048,1024]x[1024,4096]
  k_tcast<<<dim3(4096/32, 1024/32), tblk, 0, stream>>>(W_key, Wt_key, 1024, 4096);
  mfma_gemm<1,false,true><<<dim3(4096/128, BT/128), thr256, 0, stream>>>(XKbf, Wt_key, nullptr, KFbf, BT, 4096, 1024);
  // 15. KV = KFbf @ W_val  [2048,4096]x[4096,1024]
  k_tcast<<<dim3(1024/32, 4096/32), tblk, 0, stream>>>(W_val, Wt_val, 4096, 1024);
  mfma_gemm<0,false,false><<<dim3(1024/128, BT/128), thr256, 0, stream>>>(KFbf, Wt_val, KV, nullptr, BT, 1024, 4096);
  // 16. R = sigmoid(XRbf @ W_rec)
  k_tcast<<<dim3(1024/32, 1024/32), tblk, 0, stream>>>(W_rec, Wt_rec, 1024, 1024);
  mfma_gemm<2,false,false><<<dim3(1024/128, BT/128), thr256, 0, stream>>>(XRbf, Wt_rec, R, nullptr, BT, 1024, 1024);
  // 17. out = x + sigmoid_r * kv
  k_final<<<(BT*DM)/256, thr256, 0, stream>>>(X, R, KV, out);
}